// Round 1
// baseline (850.486 us; speedup 1.0000x reference)
//
#include <hip/hip_runtime.h>
#include <math.h>

#define NN 100000
#define EE 1600000
#define ET (EE + NN)
#define NB_SCAN 49   // ceil(NN/2048)

__device__ __forceinline__ float lrelu(float x) { return x > 0.f ? x : 0.2f * x; }

// ---------------- Layer 1 GEMM: h1 = x @ W1, plus per-node logits es1/ed1 ----------
// block 256: c = tid&127 (output col), half = tid>>7; rows = blockIdx*4 + half*2 + {0,1}
__global__ void k_gemm1(const float* __restrict__ x, const float* __restrict__ W1,
                        const float* __restrict__ as1, const float* __restrict__ ad1,
                        float* __restrict__ h1, float* __restrict__ es1,
                        float* __restrict__ ed1) {
    __shared__ float xs[4][128];
    int tid = threadIdx.x;
    int c = tid & 127, half = tid >> 7;
    int rbase = blockIdx.x * 4;
    for (int j = 0; j < 2; ++j) {
        int lin = tid + j * 256;          // 0..511
        int r = lin >> 7, k = lin & 127;
        int row = rbase + r;
        xs[r][k] = (row < NN) ? x[row * 128 + k] : 0.f;
    }
    __syncthreads();
    int r0 = half * 2;
    float a0 = 0.f, a1 = 0.f;
    #pragma unroll 8
    for (int k = 0; k < 128; ++k) {
        float w = W1[k * 128 + c];
        a0 += xs[r0][k] * w;
        a1 += xs[r0 + 1][k] * w;
    }
    int row0 = rbase + r0, row1 = row0 + 1;
    if (row0 < NN) h1[row0 * 128 + c] = a0;
    if (row1 < NN) h1[row1 * 128 + c] = a1;
    // attention logits: head = c>>4, att flat index = c
    float s0 = a0 * as1[c], d0 = a0 * ad1[c];
    float s1 = a1 * as1[c], d1 = a1 * ad1[c];
    for (int o = 8; o; o >>= 1) {
        s0 += __shfl_xor(s0, o); d0 += __shfl_xor(d0, o);
        s1 += __shfl_xor(s1, o); d1 += __shfl_xor(d1, o);
    }
    if ((c & 15) == 0) {
        int h = c >> 4;
        if (row0 < NN) { es1[row0 * 8 + h] = s0; ed1[row0 * 8 + h] = d0; }
        if (row1 < NN) { es1[row1 * 8 + h] = s1; ed1[row1 * 8 + h] = d1; }
    }
}

// ---------------- CSR build ----------------
__global__ void k_init_cnt(int* __restrict__ cnt) {
    int i = blockIdx.x * 256 + threadIdx.x;
    if (i < NN) cnt[i] = 1;   // self-loop
}

__global__ void k_hist(const int* __restrict__ dst, int* __restrict__ cnt) {
    int e = blockIdx.x * 256 + threadIdx.x;
    if (e < EE) atomicAdd(&cnt[dst[e]], 1);
}

__global__ void k_scan1(const int* __restrict__ cnt, int* __restrict__ rp,
                        int* __restrict__ bsum) {
    __shared__ int sd[256];
    int t = threadIdx.x;
    int base = blockIdx.x * 2048 + t * 8;
    int v[8];
    int s = 0;
    #pragma unroll
    for (int j = 0; j < 8; ++j) {
        int i = base + j;
        v[j] = (i < NN) ? cnt[i] : 0;
        s += v[j];
    }
    sd[t] = s;
    __syncthreads();
    for (int off = 1; off < 256; off <<= 1) {
        int xv = (t >= off) ? sd[t - off] : 0;
        __syncthreads();
        sd[t] += xv;
        __syncthreads();
    }
    int excl = sd[t] - s;
    if (t == 255) bsum[blockIdx.x] = sd[255];
    #pragma unroll
    for (int j = 0; j < 8; ++j) {
        int i = base + j;
        if (i < NN) rp[i] = excl;
        excl += v[j];
    }
}

__global__ void k_scan2(int* __restrict__ bsum) {
    if (threadIdx.x == 0 && blockIdx.x == 0) {
        int s = 0;
        for (int i = 0; i < NB_SCAN; ++i) { int c = bsum[i]; bsum[i] = s; s += c; }
    }
}

__global__ void k_scan3(int* __restrict__ rp, const int* __restrict__ bsum,
                        int* __restrict__ cur) {
    int i = blockIdx.x * 256 + threadIdx.x;
    if (i < NN) {
        int v = rp[i] + bsum[i >> 11];
        rp[i] = v;
        cur[i] = v;
    }
    if (i == 0) rp[NN] = ET;
}

__global__ void k_scatter(const int* __restrict__ src, const int* __restrict__ dst,
                          int* __restrict__ cur, int* __restrict__ col) {
    int e = blockIdx.x * 256 + threadIdx.x;
    if (e >= ET) return;
    int s, d;
    if (e < EE) { s = src[e]; d = dst[e]; } else { s = d = e - EE; }
    int p = atomicAdd(&cur[d], 1);
    col[p] = s;
}

// ---------------- Layer 1 aggregate: one wave per dst node -------------------------
__global__ void k_agg1(const int* __restrict__ rp, const int* __restrict__ col,
                       const float* __restrict__ h1, const float* __restrict__ es1,
                       const float* __restrict__ ed1, const float* __restrict__ b1,
                       float* __restrict__ out1) {
    int gid = blockIdx.x * blockDim.x + threadIdx.x;
    int n = gid >> 6, lane = threadIdx.x & 63;
    if (n >= NN) return;
    int hA = lane >> 4, hB = 4 + hA;   // heads for channels lane and lane+64
    float edA = ed1[n * 8 + hA], edB = ed1[n * 8 + hB];
    int beg = rp[n], end = rp[n + 1];
    float acc0 = 0.f, acc1 = 0.f, denA = 0.f, denB = 0.f;
    for (int e = beg; e < end; ++e) {
        int s = col[e];
        float exA = __expf(lrelu(es1[s * 8 + hA] + edA));
        float exB = __expf(lrelu(es1[s * 8 + hB] + edB));
        denA += exA; denB += exB;
        acc0 += exA * h1[s * 128 + lane];
        acc1 += exB * h1[s * 128 + 64 + lane];
    }
    out1[n * 128 + lane]      = fmaxf(acc0 / (denA + 1e-16f) + b1[lane], 0.f);
    out1[n * 128 + 64 + lane] = fmaxf(acc1 / (denB + 1e-16f) + b1[64 + lane], 0.f);
}

// ---------------- Layer 2 GEMM: h2 = out1 @ W2 (128 -> 40) -------------------------
__global__ void k_gemm2(const float* __restrict__ out1, const float* __restrict__ W2,
                        float* __restrict__ h2) {
    int idx = blockIdx.x * 256 + threadIdx.x;
    if (idx >= NN * 40) return;
    int row = idx / 40, c = idx - row * 40;
    const float* xr = out1 + row * 128;
    float acc = 0.f;
    #pragma unroll 4
    for (int k = 0; k < 128; ++k) acc += xr[k] * W2[k * 40 + c];
    h2[idx] = acc;
}

__global__ void k_logits2(const float* __restrict__ h2, const float* __restrict__ as2,
                          const float* __restrict__ ad2, float* __restrict__ es2,
                          float* __restrict__ ed2) {
    int n = blockIdx.x * 256 + threadIdx.x;
    if (n >= NN) return;
    const float* r = h2 + n * 40;
    float s = 0.f, d = 0.f;
    #pragma unroll
    for (int c = 0; c < 40; ++c) { float v = r[c]; s += v * as2[c]; d += v * ad2[c]; }
    es2[n] = s;
    ed2[n] = d;
}

// ---------------- Layer 2 aggregate + log_softmax: one wave per dst node -----------
__global__ void k_agg2(const int* __restrict__ rp, const int* __restrict__ col,
                       const float* __restrict__ h2, const float* __restrict__ es2,
                       const float* __restrict__ ed2, const float* __restrict__ b2,
                       float* __restrict__ out) {
    int gid = blockIdx.x * blockDim.x + threadIdx.x;
    int n = gid >> 6, lane = threadIdx.x & 63;
    if (n >= NN) return;
    float edn = ed2[n];
    int beg = rp[n], end = rp[n + 1];
    float acc = 0.f, den = 0.f;
    for (int e = beg; e < end; ++e) {
        int s = col[e];
        float ex = __expf(lrelu(es2[s] + edn));
        den += ex;
        if (lane < 40) acc += ex * h2[s * 40 + lane];
    }
    float v = (lane < 40) ? acc / (den + 1e-16f) + b2[lane] : -INFINITY;
    float m = v;
    for (int o = 32; o; o >>= 1) m = fmaxf(m, __shfl_xor(m, o));
    float ex = (lane < 40) ? __expf(v - m) : 0.f;
    float ssum = ex;
    for (int o = 32; o; o >>= 1) ssum += __shfl_xor(ssum, o);
    if (lane < 40) out[n * 40 + lane] = v - m - __logf(ssum);
}

extern "C" void kernel_launch(void* const* d_in, const int* in_sizes, int n_in,
                              void* d_out, int out_size, void* d_ws, size_t ws_size,
                              hipStream_t stream) {
    const float* x   = (const float*)d_in[0];
    const int*   ei  = (const int*)d_in[1];   // int32 (JAX x64 disabled canonicalizes int64->int32)
    const float* W1  = (const float*)d_in[2];
    const float* as1 = (const float*)d_in[3];
    const float* ad1 = (const float*)d_in[4];
    const float* b1  = (const float*)d_in[5];
    const float* W2  = (const float*)d_in[6];
    const float* as2 = (const float*)d_in[7];
    const float* ad2 = (const float*)d_in[8];
    const float* b2  = (const float*)d_in[9];
    float* out = (float*)d_out;

    const int* esrc = ei;
    const int* edst = ei + EE;

    // workspace layout (all 4-byte elements)
    float* h1   = (float*)d_ws;          // N*128
    float* es1  = h1 + NN * 128;         // N*8
    float* ed1  = es1 + NN * 8;          // N*8
    float* out1 = ed1 + NN * 8;          // N*128
    float* h2   = out1 + NN * 128;       // N*40
    float* es2  = h2 + NN * 40;          // N
    float* ed2  = es2 + NN;              // N
    int* rp     = (int*)(ed2 + NN);      // N+1
    int* cur    = rp + NN + 1;           // N
    int* bsum   = cur + NN;              // 64
    int* col    = bsum + 64;             // ET
    int* cnt    = col + ET;              // N

    // CSR build
    k_init_cnt<<<(NN + 255) / 256, 256, 0, stream>>>(cnt);
    k_hist<<<(EE + 255) / 256, 256, 0, stream>>>(edst, cnt);
    k_scan1<<<NB_SCAN, 256, 0, stream>>>(cnt, rp, bsum);
    k_scan2<<<1, 64, 0, stream>>>(bsum);
    k_scan3<<<(NN + 255) / 256, 256, 0, stream>>>(rp, bsum, cur);
    k_scatter<<<(ET + 255) / 256, 256, 0, stream>>>(esrc, edst, cur, col);

    // layer 1
    k_gemm1<<<NN / 4, 256, 0, stream>>>(x, W1, as1, ad1, h1, es1, ed1);
    k_agg1<<<(NN * 64) / 256, 256, 0, stream>>>(rp, col, h1, es1, ed1, b1, out1);

    // layer 2
    k_gemm2<<<(NN * 40 + 255) / 256, 256, 0, stream>>>(out1, W2, h2);
    k_logits2<<<(NN + 255) / 256, 256, 0, stream>>>(h2, as2, ad2, es2, ed2);
    k_agg2<<<(NN * 64) / 256, 256, 0, stream>>>(rp, col, h2, es2, ed2, b2, out);
}

// Round 2
// 661.578 us; speedup vs baseline: 1.2855x; 1.2855x over previous
//
#include <hip/hip_runtime.h>
#include <math.h>

#define NN 100000
#define EE 1600000
#define ET (EE + NN)
#define NB_SCAN 49   // ceil(NN/2048)

__device__ __forceinline__ float lrelu(float x) { return x > 0.f ? x : 0.2f * x; }

// ---------------- Layer 1 GEMM: h1 = x @ W1, plus per-node logits es1/ed1 ----------
// block 256, tile 16 rows x 128 cols; thread = 2 rows x 4 cols (float4)
__global__ void k_gemm1(const float* __restrict__ x, const float* __restrict__ W1,
                        const float* __restrict__ as1, const float* __restrict__ ad1,
                        float* __restrict__ h1, float* __restrict__ es1,
                        float* __restrict__ ed1) {
    __shared__ float xs[16][132];   // +4 pad: kills 4-way bank conflict on xs[r][k]
    int tid = threadIdx.x;
    int rbase = blockIdx.x * 16;
    for (int j = 0; j < 2; ++j) {
        int lin = tid + j * 256;          // 0..511 -> 512 float4 loads
        int r = lin >> 5, k4 = lin & 31;
        int row = rbase + r;
        float4 v = (row < NN) ? ((const float4*)x)[row * 32 + k4]
                              : make_float4(0.f, 0.f, 0.f, 0.f);
        *(float4*)&xs[r][k4 * 4] = v;
    }
    __syncthreads();
    int c4 = tid & 31;            // cols c4*4 .. c4*4+3
    int r0 = (tid >> 5) * 2, r1 = r0 + 1;
    float4 a0 = make_float4(0.f, 0.f, 0.f, 0.f);
    float4 a1 = make_float4(0.f, 0.f, 0.f, 0.f);
    const float4* W1v = (const float4*)W1;
    #pragma unroll 8
    for (int k = 0; k < 128; ++k) {
        float4 w = W1v[k * 32 + c4];
        float x0 = xs[r0][k], x1 = xs[r1][k];
        a0.x += x0 * w.x; a0.y += x0 * w.y; a0.z += x0 * w.z; a0.w += x0 * w.w;
        a1.x += x1 * w.x; a1.y += x1 * w.y; a1.z += x1 * w.z; a1.w += x1 * w.w;
    }
    int row0 = rbase + r0, row1 = rbase + r1;
    if (row0 < NN) ((float4*)h1)[row0 * 32 + c4] = a0;
    if (row1 < NN) ((float4*)h1)[row1 * 32 + c4] = a1;
    // logits: head = c4>>2 (16 ch per head, float4 never crosses a head boundary)
    float4 s4 = ((const float4*)as1)[c4], d4 = ((const float4*)ad1)[c4];
    float s0 = a0.x * s4.x + a0.y * s4.y + a0.z * s4.z + a0.w * s4.w;
    float d0 = a0.x * d4.x + a0.y * d4.y + a0.z * d4.z + a0.w * d4.w;
    float s1 = a1.x * s4.x + a1.y * s4.y + a1.z * s4.z + a1.w * s4.w;
    float d1 = a1.x * d4.x + a1.y * d4.y + a1.z * d4.z + a1.w * d4.w;
    s0 += __shfl_xor(s0, 1); s0 += __shfl_xor(s0, 2);
    d0 += __shfl_xor(d0, 1); d0 += __shfl_xor(d0, 2);
    s1 += __shfl_xor(s1, 1); s1 += __shfl_xor(s1, 2);
    d1 += __shfl_xor(d1, 1); d1 += __shfl_xor(d1, 2);
    if ((c4 & 3) == 0) {
        int h = c4 >> 2;
        if (row0 < NN) { es1[row0 * 8 + h] = s0; ed1[row0 * 8 + h] = d0; }
        if (row1 < NN) { es1[row1 * 8 + h] = s1; ed1[row1 * 8 + h] = d1; }
    }
}

// ---------------- CSR build ----------------
__global__ void k_init_cnt(int* __restrict__ cnt) {
    int i = blockIdx.x * 256 + threadIdx.x;
    if (i < NN) cnt[i] = 1;   // self-loop
}

__global__ void k_hist(const int* __restrict__ dst, int* __restrict__ cnt) {
    int e = blockIdx.x * 256 + threadIdx.x;
    if (e < EE) atomicAdd(&cnt[dst[e]], 1);
}

__global__ void k_scan1(const int* __restrict__ cnt, int* __restrict__ rp,
                        int* __restrict__ bsum) {
    __shared__ int sd[256];
    int t = threadIdx.x;
    int base = blockIdx.x * 2048 + t * 8;
    int v[8];
    int s = 0;
    #pragma unroll
    for (int j = 0; j < 8; ++j) {
        int i = base + j;
        v[j] = (i < NN) ? cnt[i] : 0;
        s += v[j];
    }
    sd[t] = s;
    __syncthreads();
    for (int off = 1; off < 256; off <<= 1) {
        int xv = (t >= off) ? sd[t - off] : 0;
        __syncthreads();
        sd[t] += xv;
        __syncthreads();
    }
    int excl = sd[t] - s;
    if (t == 255) bsum[blockIdx.x] = sd[255];
    #pragma unroll
    for (int j = 0; j < 8; ++j) {
        int i = base + j;
        if (i < NN) rp[i] = excl;
        excl += v[j];
    }
}

__global__ void k_scan2(int* __restrict__ bsum) {
    if (threadIdx.x == 0 && blockIdx.x == 0) {
        int s = 0;
        for (int i = 0; i < NB_SCAN; ++i) { int c = bsum[i]; bsum[i] = s; s += c; }
    }
}

__global__ void k_scan3(int* __restrict__ rp, const int* __restrict__ bsum,
                        int* __restrict__ cur) {
    int i = blockIdx.x * 256 + threadIdx.x;
    if (i < NN) {
        int v = rp[i] + bsum[i >> 11];
        rp[i] = v;
        cur[i] = v;
    }
    if (i == 0) rp[NN] = ET;
}

__global__ void k_scatter(const int* __restrict__ src, const int* __restrict__ dst,
                          int* __restrict__ cur, int* __restrict__ col) {
    int e = blockIdx.x * 256 + threadIdx.x;
    if (e >= ET) return;
    int s, d;
    if (e < EE) { s = src[e]; d = dst[e]; } else { s = d = e - EE; }
    int p = atomicAdd(&cur[d], 1);
    col[p] = s;
}

// ---------------- Layer 1 aggregate: one wave per dst node, 4 edges/iter ----------
__global__ void k_agg1(const int* __restrict__ rp, const int* __restrict__ col,
                       const float4* __restrict__ h1v, const float* __restrict__ es1,
                       const float* __restrict__ ed1, const float* __restrict__ b1,
                       float* __restrict__ out1) {
    int gid = blockIdx.x * blockDim.x + threadIdx.x;
    int n = gid >> 6, lane = threadIdx.x & 63;
    if (n >= NN) return;
    int g = lane >> 4;            // edge group 0..3
    int q = lane & 15;            // float4 slot: channels q*4 (A), 64+q*4 (B)
    int hA = q >> 2, hB = 4 + hA;
    float edA = ed1[n * 8 + hA], edB = ed1[n * 8 + hB];
    int beg = rp[n], end = rp[n + 1];
    float4 accA = make_float4(0.f, 0.f, 0.f, 0.f);
    float4 accB = make_float4(0.f, 0.f, 0.f, 0.f);
    float denA = 0.f, denB = 0.f;
    for (int e0 = beg; e0 < end; e0 += 4) {
        int e = e0 + g;
        bool valid = e < end;
        int s = col[valid ? e : end - 1];
        float exA = __expf(lrelu(es1[s * 8 + hA] + edA));
        float exB = __expf(lrelu(es1[s * 8 + hB] + edB));
        if (!valid) { exA = 0.f; exB = 0.f; }
        float4 va = h1v[s * 32 + q];
        float4 vb = h1v[s * 32 + 16 + q];
        accA.x += exA * va.x; accA.y += exA * va.y; accA.z += exA * va.z; accA.w += exA * va.w;
        accB.x += exB * vb.x; accB.y += exB * vb.y; accB.z += exB * vb.z; accB.w += exB * vb.w;
        denA += exA; denB += exB;
    }
    #pragma unroll
    for (int o = 16; o <= 32; o <<= 1) {
        accA.x += __shfl_xor(accA.x, o); accA.y += __shfl_xor(accA.y, o);
        accA.z += __shfl_xor(accA.z, o); accA.w += __shfl_xor(accA.w, o);
        accB.x += __shfl_xor(accB.x, o); accB.y += __shfl_xor(accB.y, o);
        accB.z += __shfl_xor(accB.z, o); accB.w += __shfl_xor(accB.w, o);
        denA += __shfl_xor(denA, o);     denB += __shfl_xor(denB, o);
    }
    if (g == 0) {
        float ia = 1.f / (denA + 1e-16f), ib = 1.f / (denB + 1e-16f);
        float4 bA = ((const float4*)b1)[q], bB = ((const float4*)b1)[16 + q];
        float4 oA, oB;
        oA.x = fmaxf(accA.x * ia + bA.x, 0.f); oA.y = fmaxf(accA.y * ia + bA.y, 0.f);
        oA.z = fmaxf(accA.z * ia + bA.z, 0.f); oA.w = fmaxf(accA.w * ia + bA.w, 0.f);
        oB.x = fmaxf(accB.x * ib + bB.x, 0.f); oB.y = fmaxf(accB.y * ib + bB.y, 0.f);
        oB.z = fmaxf(accB.z * ib + bB.z, 0.f); oB.w = fmaxf(accB.w * ib + bB.w, 0.f);
        ((float4*)out1)[n * 32 + q]      = oA;
        ((float4*)out1)[n * 32 + 16 + q] = oB;
    }
}

// ---------------- Layer 2 GEMM: h2 = out1 @ W2 (128 -> 40) -------------------------
__global__ void k_gemm2(const float* __restrict__ out1, const float* __restrict__ W2,
                        float* __restrict__ h2) {
    int idx = blockIdx.x * 256 + threadIdx.x;
    if (idx >= NN * 40) return;
    int row = idx / 40, c = idx - row * 40;
    const float* xr = out1 + row * 128;
    float acc = 0.f;
    #pragma unroll 4
    for (int k = 0; k < 128; ++k) acc += xr[k] * W2[k * 40 + c];
    h2[idx] = acc;
}

__global__ void k_logits2(const float* __restrict__ h2, const float* __restrict__ as2,
                          const float* __restrict__ ad2, float* __restrict__ es2,
                          float* __restrict__ ed2) {
    int n = blockIdx.x * 256 + threadIdx.x;
    if (n >= NN) return;
    const float* r = h2 + n * 40;
    float s = 0.f, d = 0.f;
    #pragma unroll
    for (int c = 0; c < 40; ++c) { float v = r[c]; s += v * as2[c]; d += v * ad2[c]; }
    es2[n] = s;
    ed2[n] = d;
}

// ------- Layer 2 aggregate + log_softmax: one wave per dst node, 4 edges/iter ------
__global__ void k_agg2(const int* __restrict__ rp, const int* __restrict__ col,
                       const float4* __restrict__ h2v, const float* __restrict__ es2,
                       const float* __restrict__ ed2, const float* __restrict__ b2,
                       float* __restrict__ out) {
    int gid = blockIdx.x * blockDim.x + threadIdx.x;
    int n = gid >> 6, lane = threadIdx.x & 63;
    if (n >= NN) return;
    int g = lane >> 4;            // edge group 0..3
    int q = lane & 15;            // float4 slot, valid q<10 (40 channels)
    bool qv = q < 10;
    float edn = ed2[n];
    int beg = rp[n], end = rp[n + 1];
    float4 acc = make_float4(0.f, 0.f, 0.f, 0.f);
    float den = 0.f;
    for (int e0 = beg; e0 < end; e0 += 4) {
        int e = e0 + g;
        bool valid = e < end;
        int s = col[valid ? e : end - 1];
        float ex = valid ? __expf(lrelu(es2[s] + edn)) : 0.f;
        den += ex;
        if (qv) {
            float4 v = h2v[s * 10 + q];
            acc.x += ex * v.x; acc.y += ex * v.y; acc.z += ex * v.z; acc.w += ex * v.w;
        }
    }
    #pragma unroll
    for (int o = 16; o <= 32; o <<= 1) {
        acc.x += __shfl_xor(acc.x, o); acc.y += __shfl_xor(acc.y, o);
        acc.z += __shfl_xor(acc.z, o); acc.w += __shfl_xor(acc.w, o);
        den += __shfl_xor(den, o);
    }
    float inv = 1.f / (den + 1e-16f);
    float4 v = make_float4(-INFINITY, -INFINITY, -INFINITY, -INFINITY);
    if (qv) {
        float4 b = ((const float4*)b2)[q];
        v.x = acc.x * inv + b.x; v.y = acc.y * inv + b.y;
        v.z = acc.z * inv + b.z; v.w = acc.w * inv + b.w;
    }
    float m = fmaxf(fmaxf(v.x, v.y), fmaxf(v.z, v.w));
    #pragma unroll
    for (int o = 1; o <= 8; o <<= 1) m = fmaxf(m, __shfl_xor(m, o));
    float es = 0.f;
    if (qv) es = __expf(v.x - m) + __expf(v.y - m) + __expf(v.z - m) + __expf(v.w - m);
    #pragma unroll
    for (int o = 1; o <= 8; o <<= 1) es += __shfl_xor(es, o);
    if (g == 0 && qv) {
        float ls = m + __logf(es);
        float4 o4;
        o4.x = v.x - ls; o4.y = v.y - ls; o4.z = v.z - ls; o4.w = v.w - ls;
        ((float4*)out)[n * 10 + q] = o4;
    }
}

extern "C" void kernel_launch(void* const* d_in, const int* in_sizes, int n_in,
                              void* d_out, int out_size, void* d_ws, size_t ws_size,
                              hipStream_t stream) {
    const float* x   = (const float*)d_in[0];
    const int*   ei  = (const int*)d_in[1];   // int32 (JAX x64 disabled)
    const float* W1  = (const float*)d_in[2];
    const float* as1 = (const float*)d_in[3];
    const float* ad1 = (const float*)d_in[4];
    const float* b1  = (const float*)d_in[5];
    const float* W2  = (const float*)d_in[6];
    const float* as2 = (const float*)d_in[7];
    const float* ad2 = (const float*)d_in[8];
    const float* b2  = (const float*)d_in[9];
    float* out = (float*)d_out;

    const int* esrc = ei;
    const int* edst = ei + EE;

    // workspace layout (all 4-byte elements)
    float* h1   = (float*)d_ws;          // N*128
    float* es1  = h1 + NN * 128;         // N*8
    float* ed1  = es1 + NN * 8;          // N*8
    float* out1 = ed1 + NN * 8;          // N*128
    float* h2   = out1 + NN * 128;       // N*40
    float* es2  = h2 + NN * 40;          // N
    float* ed2  = es2 + NN;              // N
    int* rp     = (int*)(ed2 + NN);      // N+1
    int* cur    = rp + NN + 1;           // N
    int* bsum   = cur + NN;              // 64
    int* col    = bsum + 64;             // ET
    int* cnt    = col + ET;              // N

    // CSR build
    k_init_cnt<<<(NN + 255) / 256, 256, 0, stream>>>(cnt);
    k_hist<<<(EE + 255) / 256, 256, 0, stream>>>(edst, cnt);
    k_scan1<<<NB_SCAN, 256, 0, stream>>>(cnt, rp, bsum);
    k_scan2<<<1, 64, 0, stream>>>(bsum);
    k_scan3<<<(NN + 255) / 256, 256, 0, stream>>>(rp, bsum, cur);
    k_scatter<<<(ET + 255) / 256, 256, 0, stream>>>(esrc, edst, cur, col);

    // layer 1
    k_gemm1<<<NN / 16, 256, 0, stream>>>(x, W1, as1, ad1, h1, es1, ed1);
    k_agg1<<<(NN * 64) / 256, 256, 0, stream>>>(rp, col, (const float4*)h1, es1, ed1, b1, out1);

    // layer 2
    k_gemm2<<<(NN * 40 + 255) / 256, 256, 0, stream>>>(out1, W2, h2);
    k_logits2<<<(NN + 255) / 256, 256, 0, stream>>>(h2, as2, ad2, es2, ed2);
    k_agg2<<<(NN * 64) / 256, 256, 0, stream>>>(rp, col, (const float4*)h2, es2, ed2, b2, out);
}

// Round 4
// 606.790 us; speedup vs baseline: 1.4016x; 1.0903x over previous
//
#include <hip/hip_runtime.h>
#include <hip/hip_fp16.h>
#include <math.h>

#define NN 100000
#define EE 1600000
#define ET (EE + NN)
#define NB_SCAN 49   // ceil(NN/2048)

__device__ __forceinline__ float lrelu(float x) { return x > 0.f ? x : 0.2f * x; }

// ---------------- Layer 1 GEMM: h1h (fp16) = x @ W1, plus logits es1/ed1 -----------
// block 256, tile 16 rows x 128 cols; thread = 2 rows x 4 cols (float4)
__global__ void k_gemm1(const float* __restrict__ x, const float* __restrict__ W1,
                        const float* __restrict__ as1, const float* __restrict__ ad1,
                        __half* __restrict__ h1h, float* __restrict__ es1,
                        float* __restrict__ ed1) {
    __shared__ float xs[16][132];   // +4 pad: kills 4-way bank conflict
    int tid = threadIdx.x;
    int rbase = blockIdx.x * 16;
    for (int j = 0; j < 2; ++j) {
        int lin = tid + j * 256;          // 0..511 -> 512 float4 loads
        int r = lin >> 5, k4 = lin & 31;
        int row = rbase + r;
        float4 v = (row < NN) ? ((const float4*)x)[row * 32 + k4]
                              : make_float4(0.f, 0.f, 0.f, 0.f);
        *(float4*)&xs[r][k4 * 4] = v;
    }
    __syncthreads();
    int c4 = tid & 31;            // cols c4*4 .. c4*4+3
    int r0 = (tid >> 5) * 2, r1 = r0 + 1;
    float4 a0 = make_float4(0.f, 0.f, 0.f, 0.f);
    float4 a1 = make_float4(0.f, 0.f, 0.f, 0.f);
    const float4* W1v = (const float4*)W1;
    #pragma unroll 8
    for (int k = 0; k < 128; ++k) {
        float4 w = W1v[k * 32 + c4];
        float x0 = xs[r0][k], x1 = xs[r1][k];
        a0.x += x0 * w.x; a0.y += x0 * w.y; a0.z += x0 * w.z; a0.w += x0 * w.w;
        a1.x += x1 * w.x; a1.y += x1 * w.y; a1.z += x1 * w.z; a1.w += x1 * w.w;
    }
    int row0 = rbase + r0, row1 = rbase + r1;
    union { __half2 h[2]; uint2 u; } cv0, cv1;
    cv0.h[0] = __floats2half2_rn(a0.x, a0.y); cv0.h[1] = __floats2half2_rn(a0.z, a0.w);
    cv1.h[0] = __floats2half2_rn(a1.x, a1.y); cv1.h[1] = __floats2half2_rn(a1.z, a1.w);
    if (row0 < NN) ((uint2*)h1h)[row0 * 32 + c4] = cv0.u;
    if (row1 < NN) ((uint2*)h1h)[row1 * 32 + c4] = cv1.u;
    // logits: head = c4>>2
    float4 s4 = ((const float4*)as1)[c4], d4 = ((const float4*)ad1)[c4];
    float s0 = a0.x * s4.x + a0.y * s4.y + a0.z * s4.z + a0.w * s4.w;
    float d0 = a0.x * d4.x + a0.y * d4.y + a0.z * d4.z + a0.w * d4.w;
    float s1 = a1.x * s4.x + a1.y * s4.y + a1.z * s4.z + a1.w * s4.w;
    float d1 = a1.x * d4.x + a1.y * d4.y + a1.z * d4.z + a1.w * d4.w;
    s0 += __shfl_xor(s0, 1); s0 += __shfl_xor(s0, 2);
    d0 += __shfl_xor(d0, 1); d0 += __shfl_xor(d0, 2);
    s1 += __shfl_xor(s1, 1); s1 += __shfl_xor(s1, 2);
    d1 += __shfl_xor(d1, 1); d1 += __shfl_xor(d1, 2);
    if ((c4 & 3) == 0) {
        int h = c4 >> 2;
        if (row0 < NN) { es1[row0 * 8 + h] = s0; ed1[row0 * 8 + h] = d0; }
        if (row1 < NN) { es1[row1 * 8 + h] = s1; ed1[row1 * 8 + h] = d1; }
    }
}

// ---------------- CSR build ----------------
__global__ void k_init_cnt(int* __restrict__ cnt) {
    int i = blockIdx.x * 256 + threadIdx.x;
    if (i < NN) cnt[i] = 1;   // self-loop
}

__global__ void k_hist(const int* __restrict__ dst, int* __restrict__ cnt) {
    int e = blockIdx.x * 256 + threadIdx.x;
    if (e < EE) atomicAdd(&cnt[dst[e]], 1);
}

__global__ void k_scan1(const int* __restrict__ cnt, int* __restrict__ rp,
                        int* __restrict__ bsum) {
    __shared__ int sd[256];
    int t = threadIdx.x;
    int base = blockIdx.x * 2048 + t * 8;
    int v[8];
    int s = 0;
    #pragma unroll
    for (int j = 0; j < 8; ++j) {
        int i = base + j;
        v[j] = (i < NN) ? cnt[i] : 0;
        s += v[j];
    }
    sd[t] = s;
    __syncthreads();
    for (int off = 1; off < 256; off <<= 1) {
        int xv = (t >= off) ? sd[t - off] : 0;
        __syncthreads();
        sd[t] += xv;
        __syncthreads();
    }
    int excl = sd[t] - s;
    if (t == 255) bsum[blockIdx.x] = sd[255];
    #pragma unroll
    for (int j = 0; j < 8; ++j) {
        int i = base + j;
        if (i < NN) rp[i] = excl;
        excl += v[j];
    }
}

__global__ void k_scan2(int* __restrict__ bsum) {
    if (threadIdx.x == 0 && blockIdx.x == 0) {
        int s = 0;
        for (int i = 0; i < NB_SCAN; ++i) { int c = bsum[i]; bsum[i] = s; s += c; }
    }
}

__global__ void k_scan3(int* __restrict__ rp, const int* __restrict__ bsum,
                        int* __restrict__ cur) {
    int i = blockIdx.x * 256 + threadIdx.x;
    if (i < NN) {
        int v = rp[i] + bsum[i >> 11];
        rp[i] = v;
        cur[i] = v;
    }
    if (i == 0) rp[NN] = ET;
}

__global__ void k_scatter(const int* __restrict__ src, const int* __restrict__ dst,
                          int* __restrict__ cur, int* __restrict__ col) {
    int e = blockIdx.x * 256 + threadIdx.x;
    if (e >= ET) return;
    int s, d;
    if (e < EE) { s = src[e]; d = dst[e]; } else { s = d = e - EE; }
    int p = atomicAdd(&cur[d], 1);
    col[p] = s;
}

// ---- Determinism fix: sort each node's col segment by value (wave bitonic) --------
// atomicAdd in k_scatter makes within-bucket order vary per call; a value-sorted
// segment is a deterministic sequence (duplicates are numerically interchangeable),
// making every downstream fp op bit-identical across calls.
__global__ void k_sortcol(const int* __restrict__ rp, int* __restrict__ col) {
    int gid = blockIdx.x * blockDim.x + threadIdx.x;
    int n = gid >> 6, lane = threadIdx.x & 63;
    if (n >= NN) return;
    int beg = rp[n], end = rp[n + 1];
    int d = end - beg;
    if (d <= 1) return;
    if (d <= 64) {
        int v = (lane < d) ? col[beg + lane] : 0x7fffffff;
        #pragma unroll
        for (int k = 2; k <= 64; k <<= 1) {
            #pragma unroll
            for (int j = k >> 1; j > 0; j >>= 1) {
                int other = __shfl_xor(v, j);
                bool lower = (lane & j) == 0;
                bool up = (lane & k) == 0;
                v = (lower == up) ? min(v, other) : max(v, other);
            }
        }
        if (lane < d) col[beg + lane] = v;
    } else {
        if (lane == 0) {   // degree>64: ~impossible for Poisson(17); correct fallback
            for (int i = beg + 1; i < end; ++i) {
                int key = col[i]; int j = i - 1;
                while (j >= beg && col[j] > key) { col[j + 1] = col[j]; --j; }
                col[j + 1] = key;
            }
        }
    }
}

// ------- Layer 1 aggregate: wave per node, 8 edges/iter, lane = head q, 16 ch ------
__global__ void k_agg1(const int* __restrict__ rp, const int* __restrict__ col,
                       const __half* __restrict__ h1h, const float* __restrict__ es1,
                       const float* __restrict__ ed1, const float* __restrict__ b1,
                       float* __restrict__ out1) {
    int gid = blockIdx.x * blockDim.x + threadIdx.x;
    int n = gid >> 6, lane = threadIdx.x & 63;
    if (n >= NN) return;
    int g = lane >> 3;            // edge group 0..7
    int q = lane & 7;             // head q, channels q*16 .. q*16+15
    float edn = ed1[n * 8 + q];
    int beg = rp[n], end = rp[n + 1];
    const uint4* h1v = (const uint4*)h1h;   // 8 fp16 each; 16 per row
    float acc[16];
    #pragma unroll
    for (int j = 0; j < 16; ++j) acc[j] = 0.f;
    float den = 0.f;
    for (int e0 = beg; e0 < end; e0 += 8) {
        int e = e0 + g;
        if (e < end) {
            int s = col[e];
            float ex = __expf(lrelu(es1[s * 8 + q] + edn));
            den += ex;
            uint4 u0 = h1v[s * 16 + q * 2];
            uint4 u1 = h1v[s * 16 + q * 2 + 1];
            const __half2* hp0 = (const __half2*)&u0;
            const __half2* hp1 = (const __half2*)&u1;
            #pragma unroll
            for (int j = 0; j < 4; ++j) {
                float2 f0 = __half22float2(hp0[j]);
                float2 f1 = __half22float2(hp1[j]);
                acc[j * 2]     += ex * f0.x; acc[j * 2 + 1] += ex * f0.y;
                acc[8 + j * 2] += ex * f1.x; acc[9 + j * 2] += ex * f1.y;
            }
        }
    }
    #pragma unroll
    for (int o = 8; o <= 32; o <<= 1) {
        #pragma unroll
        for (int j = 0; j < 16; ++j) acc[j] += __shfl_xor(acc[j], o);
        den += __shfl_xor(den, o);
    }
    if (g == 0) {
        float inv = 1.f / (den + 1e-16f);
        #pragma unroll
        for (int i = 0; i < 4; ++i) {
            float4 b = ((const float4*)b1)[q * 4 + i];
            float4 o4;
            o4.x = fmaxf(acc[i * 4]     * inv + b.x, 0.f);
            o4.y = fmaxf(acc[i * 4 + 1] * inv + b.y, 0.f);
            o4.z = fmaxf(acc[i * 4 + 2] * inv + b.z, 0.f);
            o4.w = fmaxf(acc[i * 4 + 3] * inv + b.w, 0.f);
            ((float4*)out1)[n * 32 + q * 4 + i] = o4;
        }
    }
}

// ---------------- Layer 2 GEMM: h2h (fp16) = out1 @ W2 (128 -> 40) -----------------
__global__ void k_gemm2(const float* __restrict__ out1, const float* __restrict__ W2,
                        __half* __restrict__ h2h) {
    int idx = blockIdx.x * 256 + threadIdx.x;
    if (idx >= NN * 40) return;
    int row = idx / 40, c = idx - row * 40;
    const float* xr = out1 + row * 128;
    float acc = 0.f;
    #pragma unroll 4
    for (int k = 0; k < 128; ++k) acc += xr[k] * W2[k * 40 + c];
    h2h[idx] = __float2half_rn(acc);
}

__global__ void k_logits2(const __half* __restrict__ h2h, const float* __restrict__ as2,
                          const float* __restrict__ ad2, float* __restrict__ es2,
                          float* __restrict__ ed2) {
    int n = blockIdx.x * 256 + threadIdx.x;
    if (n >= NN) return;
    const uint4* r = (const uint4*)h2h + n * 5;
    float s = 0.f, d = 0.f;
    #pragma unroll
    for (int c4 = 0; c4 < 5; ++c4) {
        uint4 u = r[c4];
        const __half2* hp = (const __half2*)&u;
        #pragma unroll
        for (int j = 0; j < 4; ++j) {
            float2 f = __half22float2(hp[j]);
            int c = c4 * 8 + j * 2;
            s += f.x * as2[c] + f.y * as2[c + 1];
            d += f.x * ad2[c] + f.y * ad2[c + 1];
        }
    }
    es2[n] = s;
    ed2[n] = d;
}

// -- Layer 2 aggregate + log_softmax: wave per node, 8 edges/iter, lane q<5: 8 ch ---
__global__ void k_agg2(const int* __restrict__ rp, const int* __restrict__ col,
                       const __half* __restrict__ h2h, const float* __restrict__ es2,
                       const float* __restrict__ ed2, const float* __restrict__ b2,
                       float* __restrict__ out) {
    int gid = blockIdx.x * blockDim.x + threadIdx.x;
    int n = gid >> 6, lane = threadIdx.x & 63;
    if (n >= NN) return;
    int g = lane >> 3;            // edge group 0..7
    int q = lane & 7;             // channel block q*8..q*8+7, valid q<5
    bool qv = q < 5;
    float edn = ed2[n];
    int beg = rp[n], end = rp[n + 1];
    const uint4* h2v = (const uint4*)h2h;   // 5 uint4 per row
    float acc[8];
    #pragma unroll
    for (int j = 0; j < 8; ++j) acc[j] = 0.f;
    float den = 0.f;
    for (int e0 = beg; e0 < end; e0 += 8) {
        int e = e0 + g;
        if (e < end) {
            int s = col[e];
            float ex = __expf(lrelu(es2[s] + edn));
            den += ex;
            if (qv) {
                uint4 u = h2v[s * 5 + q];
                const __half2* hp = (const __half2*)&u;
                #pragma unroll
                for (int j = 0; j < 4; ++j) {
                    float2 f = __half22float2(hp[j]);
                    acc[j * 2]     += ex * f.x;
                    acc[j * 2 + 1] += ex * f.y;
                }
            }
        }
    }
    #pragma unroll
    for (int o = 8; o <= 32; o <<= 1) {
        #pragma unroll
        for (int j = 0; j < 8; ++j) acc[j] += __shfl_xor(acc[j], o);
        den += __shfl_xor(den, o);
    }
    // every lane now holds the reduced per-q values (g-copies identical)
    float inv = 1.f / (den + 1e-16f);
    float v[8];
    float m = -INFINITY;
    if (qv) {
        #pragma unroll
        for (int j = 0; j < 8; ++j) {
            v[j] = acc[j] * inv + b2[q * 8 + j];
            m = fmaxf(m, v[j]);
        }
    }
    #pragma unroll
    for (int o = 1; o <= 4; o <<= 1) m = fmaxf(m, __shfl_xor(m, o));
    float es = 0.f;
    if (qv) {
        #pragma unroll
        for (int j = 0; j < 8; ++j) es += __expf(v[j] - m);
    }
    #pragma unroll
    for (int o = 1; o <= 4; o <<= 1) es += __shfl_xor(es, o);
    if (g == 0 && qv) {
        float ls = m + __logf(es);
        float4 o0, o1;
        o0.x = v[0] - ls; o0.y = v[1] - ls; o0.z = v[2] - ls; o0.w = v[3] - ls;
        o1.x = v[4] - ls; o1.y = v[5] - ls; o1.z = v[6] - ls; o1.w = v[7] - ls;
        ((float4*)out)[n * 10 + q * 2]     = o0;
        ((float4*)out)[n * 10 + q * 2 + 1] = o1;
    }
}

extern "C" void kernel_launch(void* const* d_in, const int* in_sizes, int n_in,
                              void* d_out, int out_size, void* d_ws, size_t ws_size,
                              hipStream_t stream) {
    const float* x   = (const float*)d_in[0];
    const int*   ei  = (const int*)d_in[1];   // int32 (JAX x64 disabled)
    const float* W1  = (const float*)d_in[2];
    const float* as1 = (const float*)d_in[3];
    const float* ad1 = (const float*)d_in[4];
    const float* b1  = (const float*)d_in[5];
    const float* W2  = (const float*)d_in[6];
    const float* as2 = (const float*)d_in[7];
    const float* ad2 = (const float*)d_in[8];
    const float* b2  = (const float*)d_in[9];
    float* out = (float*)d_out;

    const int* esrc = ei;
    const int* edst = ei + EE;

    // workspace layout
    __half* h1h = (__half*)d_ws;               // N*128 fp16 (25.6 MB)
    float* es1  = (float*)(h1h + NN * 128);    // N*8
    float* ed1  = es1 + NN * 8;                // N*8
    float* out1 = ed1 + NN * 8;                // N*128 fp32
    __half* h2h = (__half*)(out1 + NN * 128);  // N*40 fp16
    float* es2  = (float*)(h2h + NN * 40);     // N
    float* ed2  = es2 + NN;                    // N
    int* rp     = (int*)(ed2 + NN);            // N+1
    int* cur    = rp + NN + 1;                 // N
    int* bsum   = cur + NN;                    // 64
    int* col    = bsum + 64;                   // ET
    int* cnt    = col + ET;                    // N

    // CSR build (deterministic: scatter + per-node value sort)
    k_init_cnt<<<(NN + 255) / 256, 256, 0, stream>>>(cnt);
    k_hist<<<(EE + 255) / 256, 256, 0, stream>>>(edst, cnt);
    k_scan1<<<NB_SCAN, 256, 0, stream>>>(cnt, rp, bsum);
    k_scan2<<<1, 64, 0, stream>>>(bsum);
    k_scan3<<<(NN + 255) / 256, 256, 0, stream>>>(rp, bsum, cur);
    k_scatter<<<(ET + 255) / 256, 256, 0, stream>>>(esrc, edst, cur, col);
    k_sortcol<<<(NN * 64) / 256, 256, 0, stream>>>(rp, col);

    // layer 1
    k_gemm1<<<NN / 16, 256, 0, stream>>>(x, W1, as1, ad1, h1h, es1, ed1);
    k_agg1<<<(NN * 64) / 256, 256, 0, stream>>>(rp, col, h1h, es1, ed1, b1, out1);

    // layer 2
    k_gemm2<<<(NN * 40 + 255) / 256, 256, 0, stream>>>(out1, W2, h2h);
    k_logits2<<<(NN + 255) / 256, 256, 0, stream>>>(h2h, as2, ad2, es2, ed2);
    k_agg2<<<(NN * 64) / 256, 256, 0, stream>>>(rp, col, h2h, es2, ed2, b2, out);
}

// Round 5
// 523.916 us; speedup vs baseline: 1.6233x; 1.1582x over previous
//
#include <hip/hip_runtime.h>
#include <hip/hip_fp16.h>
#include <math.h>

#define NN 100000
#define EE 1600000
#define ET (EE + NN)
#define NB_SCAN 49   // ceil(NN/2048)

__device__ __forceinline__ float lrelu(float x) { return x > 0.f ? x : 0.2f * x; }

// ---------------- Layer 1 GEMM: h1h (fp16) = x @ W1, plus logits es1/ed1 -----------
// block 256, tile 16 rows x 128 cols; thread = 2 rows x 4 cols (float4)
__global__ void k_gemm1(const float* __restrict__ x, const float* __restrict__ W1,
                        const float* __restrict__ as1, const float* __restrict__ ad1,
                        __half* __restrict__ h1h, float* __restrict__ es1,
                        float* __restrict__ ed1) {
    __shared__ float xs[16][132];   // +4 pad: kills 4-way bank conflict
    int tid = threadIdx.x;
    int rbase = blockIdx.x * 16;
    for (int j = 0; j < 2; ++j) {
        int lin = tid + j * 256;          // 0..511 -> 512 float4 loads
        int r = lin >> 5, k4 = lin & 31;
        int row = rbase + r;
        float4 v = (row < NN) ? ((const float4*)x)[row * 32 + k4]
                              : make_float4(0.f, 0.f, 0.f, 0.f);
        *(float4*)&xs[r][k4 * 4] = v;
    }
    __syncthreads();
    int c4 = tid & 31;            // cols c4*4 .. c4*4+3
    int r0 = (tid >> 5) * 2, r1 = r0 + 1;
    float4 a0 = make_float4(0.f, 0.f, 0.f, 0.f);
    float4 a1 = make_float4(0.f, 0.f, 0.f, 0.f);
    const float4* W1v = (const float4*)W1;
    #pragma unroll 8
    for (int k = 0; k < 128; ++k) {
        float4 w = W1v[k * 32 + c4];
        float x0 = xs[r0][k], x1 = xs[r1][k];
        a0.x += x0 * w.x; a0.y += x0 * w.y; a0.z += x0 * w.z; a0.w += x0 * w.w;
        a1.x += x1 * w.x; a1.y += x1 * w.y; a1.z += x1 * w.z; a1.w += x1 * w.w;
    }
    int row0 = rbase + r0, row1 = rbase + r1;
    union { __half2 h[2]; uint2 u; } cv0, cv1;
    cv0.h[0] = __floats2half2_rn(a0.x, a0.y); cv0.h[1] = __floats2half2_rn(a0.z, a0.w);
    cv1.h[0] = __floats2half2_rn(a1.x, a1.y); cv1.h[1] = __floats2half2_rn(a1.z, a1.w);
    if (row0 < NN) ((uint2*)h1h)[row0 * 32 + c4] = cv0.u;
    if (row1 < NN) ((uint2*)h1h)[row1 * 32 + c4] = cv1.u;
    // logits: head = c4>>2
    float4 s4 = ((const float4*)as1)[c4], d4 = ((const float4*)ad1)[c4];
    float s0 = a0.x * s4.x + a0.y * s4.y + a0.z * s4.z + a0.w * s4.w;
    float d0 = a0.x * d4.x + a0.y * d4.y + a0.z * d4.z + a0.w * d4.w;
    float s1 = a1.x * s4.x + a1.y * s4.y + a1.z * s4.z + a1.w * s4.w;
    float d1 = a1.x * d4.x + a1.y * d4.y + a1.z * d4.z + a1.w * d4.w;
    s0 += __shfl_xor(s0, 1); s0 += __shfl_xor(s0, 2);
    d0 += __shfl_xor(d0, 1); d0 += __shfl_xor(d0, 2);
    s1 += __shfl_xor(s1, 1); s1 += __shfl_xor(s1, 2);
    d1 += __shfl_xor(d1, 1); d1 += __shfl_xor(d1, 2);
    if ((c4 & 3) == 0) {
        int h = c4 >> 2;
        if (row0 < NN) { es1[row0 * 8 + h] = s0; ed1[row0 * 8 + h] = d0; }
        if (row1 < NN) { es1[row1 * 8 + h] = s1; ed1[row1 * 8 + h] = d1; }
    }
}

// ---------------- CSR build ----------------
__global__ void k_init_cnt(int* __restrict__ cnt) {
    int i = blockIdx.x * 256 + threadIdx.x;
    if (i < NN) cnt[i] = 1;   // self-loop
}

__global__ void k_hist(const int* __restrict__ dst, int* __restrict__ cnt) {
    int e = blockIdx.x * 256 + threadIdx.x;
    if (e < EE) atomicAdd(&cnt[dst[e]], 1);
}

__global__ void k_scan1(const int* __restrict__ cnt, int* __restrict__ rp,
                        int* __restrict__ bsum) {
    __shared__ int sd[256];
    int t = threadIdx.x;
    int base = blockIdx.x * 2048 + t * 8;
    int v[8];
    int s = 0;
    #pragma unroll
    for (int j = 0; j < 8; ++j) {
        int i = base + j;
        v[j] = (i < NN) ? cnt[i] : 0;
        s += v[j];
    }
    sd[t] = s;
    __syncthreads();
    for (int off = 1; off < 256; off <<= 1) {
        int xv = (t >= off) ? sd[t - off] : 0;
        __syncthreads();
        sd[t] += xv;
        __syncthreads();
    }
    int excl = sd[t] - s;
    if (t == 255) bsum[blockIdx.x] = sd[255];
    #pragma unroll
    for (int j = 0; j < 8; ++j) {
        int i = base + j;
        if (i < NN) rp[i] = excl;
        excl += v[j];
    }
}

__global__ void k_scan2(int* __restrict__ bsum) {
    if (threadIdx.x == 0 && blockIdx.x == 0) {
        int s = 0;
        for (int i = 0; i < NB_SCAN; ++i) { int c = bsum[i]; bsum[i] = s; s += c; }
    }
}

__global__ void k_scan3(int* __restrict__ rp, const int* __restrict__ bsum,
                        int* __restrict__ cur) {
    int i = blockIdx.x * 256 + threadIdx.x;
    if (i < NN) {
        int v = rp[i] + bsum[i >> 11];
        rp[i] = v;
        cur[i] = v;
    }
    if (i == 0) rp[NN] = ET;
}

__global__ void k_scatter(const int* __restrict__ src, const int* __restrict__ dst,
                          int* __restrict__ cur, int* __restrict__ col) {
    int e = blockIdx.x * 256 + threadIdx.x;
    if (e >= ET) return;
    int s, d;
    if (e < EE) { s = src[e]; d = dst[e]; } else { s = d = e - EE; }
    int p = atomicAdd(&cur[d], 1);
    col[p] = s;
}

// ---- Determinism fix: sort each node's col segment by value (wave bitonic) --------
__global__ void k_sortcol(const int* __restrict__ rp, int* __restrict__ col) {
    int gid = blockIdx.x * blockDim.x + threadIdx.x;
    int n = gid >> 6, lane = threadIdx.x & 63;
    if (n >= NN) return;
    int beg = rp[n], end = rp[n + 1];
    int d = end - beg;
    if (d <= 1) return;
    if (d <= 64) {
        int v = (lane < d) ? col[beg + lane] : 0x7fffffff;
        #pragma unroll
        for (int k = 2; k <= 64; k <<= 1) {
            #pragma unroll
            for (int j = k >> 1; j > 0; j >>= 1) {
                int other = __shfl_xor(v, j);
                bool lower = (lane & j) == 0;
                bool up = (lane & k) == 0;
                v = (lower == up) ? min(v, other) : max(v, other);
            }
        }
        if (lane < d) col[beg + lane] = v;
    } else {
        if (lane == 0) {   // degree>64: ~impossible for Poisson(17); correct fallback
            for (int i = beg + 1; i < end; ++i) {
                int key = col[i]; int j = i - 1;
                while (j >= beg && col[j] > key) { col[j + 1] = col[j]; --j; }
                col[j + 1] = key;
            }
        }
    }
}

// ------- Layer 1 aggregate: wave per node, 8 edges/iter, lane = head q, 16 ch ------
__global__ void k_agg1(const int* __restrict__ rp, const int* __restrict__ col,
                       const __half* __restrict__ h1h, const float* __restrict__ es1,
                       const float* __restrict__ ed1, const float* __restrict__ b1,
                       float* __restrict__ out1) {
    int gid = blockIdx.x * blockDim.x + threadIdx.x;
    int n = gid >> 6, lane = threadIdx.x & 63;
    if (n >= NN) return;
    int g = lane >> 3;            // edge group 0..7
    int q = lane & 7;             // head q, channels q*16 .. q*16+15
    float edn = ed1[n * 8 + q];
    int beg = rp[n], end = rp[n + 1];
    const uint4* h1v = (const uint4*)h1h;   // 8 fp16 each; 16 per row
    float acc[16];
    #pragma unroll
    for (int j = 0; j < 16; ++j) acc[j] = 0.f;
    float den = 0.f;
    for (int e0 = beg; e0 < end; e0 += 8) {
        int e = e0 + g;
        if (e < end) {
            int s = col[e];
            float ex = __expf(lrelu(es1[s * 8 + q] + edn));
            den += ex;
            uint4 u0 = h1v[s * 16 + q * 2];
            uint4 u1 = h1v[s * 16 + q * 2 + 1];
            const __half2* hp0 = (const __half2*)&u0;
            const __half2* hp1 = (const __half2*)&u1;
            #pragma unroll
            for (int j = 0; j < 4; ++j) {
                float2 f0 = __half22float2(hp0[j]);
                float2 f1 = __half22float2(hp1[j]);
                acc[j * 2]     += ex * f0.x; acc[j * 2 + 1] += ex * f0.y;
                acc[8 + j * 2] += ex * f1.x; acc[9 + j * 2] += ex * f1.y;
            }
        }
    }
    #pragma unroll
    for (int o = 8; o <= 32; o <<= 1) {
        #pragma unroll
        for (int j = 0; j < 16; ++j) acc[j] += __shfl_xor(acc[j], o);
        den += __shfl_xor(den, o);
    }
    if (g == 0) {
        float inv = 1.f / (den + 1e-16f);
        #pragma unroll
        for (int i = 0; i < 4; ++i) {
            float4 b = ((const float4*)b1)[q * 4 + i];
            float4 o4;
            o4.x = fmaxf(acc[i * 4]     * inv + b.x, 0.f);
            o4.y = fmaxf(acc[i * 4 + 1] * inv + b.y, 0.f);
            o4.z = fmaxf(acc[i * 4 + 2] * inv + b.z, 0.f);
            o4.w = fmaxf(acc[i * 4 + 3] * inv + b.w, 0.f);
            ((float4*)out1)[n * 32 + q * 4 + i] = o4;
        }
    }
}

// ------- Layer 2 GEMM + logits, fused: thread-per-row, 40 acc in VGPRs -------------
// W2 row address is wave-uniform per k -> s_load (SMEM pipe); rows staged via LDS
// in 4 k-chunks, transposed [k][row] so compute reads are stride-1 (conflict-free).
__global__ __launch_bounds__(256) void k_gemm2(
        const float* __restrict__ out1, const float* __restrict__ W2,
        const float* __restrict__ as2, const float* __restrict__ ad2,
        __half* __restrict__ h2h, float* __restrict__ es2, float* __restrict__ ed2) {
    __shared__ float xs[32][257];   // 32 k-slots x 256 rows (+1 pad)
    int tid = threadIdx.x;
    int rbase = blockIdx.x * 256;
    int row = rbase + tid;
    float acc[40];
    #pragma unroll
    for (int c = 0; c < 40; ++c) acc[c] = 0.f;
    for (int ch = 0; ch < 4; ++ch) {
        __syncthreads();   // protect xs reuse
        #pragma unroll
        for (int i = 0; i < 8; ++i) {
            int idx = tid + i * 256;          // 0..2047
            int r = idx >> 3, j4 = idx & 7;   // r: row-in-block, j4: float4 within chunk
            int rr = rbase + r;
            float4 v = (rr < NN) ? ((const float4*)out1)[rr * 32 + ch * 8 + j4]
                                 : make_float4(0.f, 0.f, 0.f, 0.f);
            xs[j4 * 4 + 0][r] = v.x;
            xs[j4 * 4 + 1][r] = v.y;
            xs[j4 * 4 + 2][r] = v.z;
            xs[j4 * 4 + 3][r] = v.w;
        }
        __syncthreads();
        #pragma unroll 4
        for (int j = 0; j < 32; ++j) {
            float xk = xs[j][tid];
            const float* wrow = W2 + (ch * 32 + j) * 40;   // uniform -> s_load
            #pragma unroll
            for (int c = 0; c < 40; ++c) acc[c] += xk * wrow[c];
        }
    }
    if (row < NN) {
        float s = 0.f, d = 0.f;
        #pragma unroll
        for (int c = 0; c < 40; ++c) { s += acc[c] * as2[c]; d += acc[c] * ad2[c]; }
        es2[row] = s;
        ed2[row] = d;
        union { __half2 h[20]; uint4 u[5]; } cv;
        #pragma unroll
        for (int c = 0; c < 20; ++c)
            cv.h[c] = __floats2half2_rn(acc[c * 2], acc[c * 2 + 1]);
        #pragma unroll
        for (int i = 0; i < 5; ++i) ((uint4*)h2h)[row * 5 + i] = cv.u[i];
    }
}

// -- Layer 2 aggregate + log_softmax: wave per node, 8 edges/iter, lane q<5: 8 ch ---
__global__ void k_agg2(const int* __restrict__ rp, const int* __restrict__ col,
                       const __half* __restrict__ h2h, const float* __restrict__ es2,
                       const float* __restrict__ ed2, const float* __restrict__ b2,
                       float* __restrict__ out) {
    int gid = blockIdx.x * blockDim.x + threadIdx.x;
    int n = gid >> 6, lane = threadIdx.x & 63;
    if (n >= NN) return;
    int g = lane >> 3;            // edge group 0..7
    int q = lane & 7;             // channel block q*8..q*8+7, valid q<5
    bool qv = q < 5;
    float edn = ed2[n];
    int beg = rp[n], end = rp[n + 1];
    const uint4* h2v = (const uint4*)h2h;   // 5 uint4 per row
    float acc[8];
    #pragma unroll
    for (int j = 0; j < 8; ++j) acc[j] = 0.f;
    float den = 0.f;
    for (int e0 = beg; e0 < end; e0 += 8) {
        int e = e0 + g;
        if (e < end) {
            int s = col[e];
            float ex = __expf(lrelu(es2[s] + edn));
            den += ex;
            if (qv) {
                uint4 u = h2v[s * 5 + q];
                const __half2* hp = (const __half2*)&u;
                #pragma unroll
                for (int j = 0; j < 4; ++j) {
                    float2 f = __half22float2(hp[j]);
                    acc[j * 2]     += ex * f.x;
                    acc[j * 2 + 1] += ex * f.y;
                }
            }
        }
    }
    #pragma unroll
    for (int o = 8; o <= 32; o <<= 1) {
        #pragma unroll
        for (int j = 0; j < 8; ++j) acc[j] += __shfl_xor(acc[j], o);
        den += __shfl_xor(den, o);
    }
    float inv = 1.f / (den + 1e-16f);
    float v[8];
    float m = -INFINITY;
    if (qv) {
        #pragma unroll
        for (int j = 0; j < 8; ++j) {
            v[j] = acc[j] * inv + b2[q * 8 + j];
            m = fmaxf(m, v[j]);
        }
    }
    #pragma unroll
    for (int o = 1; o <= 4; o <<= 1) m = fmaxf(m, __shfl_xor(m, o));
    float es = 0.f;
    if (qv) {
        #pragma unroll
        for (int j = 0; j < 8; ++j) es += __expf(v[j] - m);
    }
    #pragma unroll
    for (int o = 1; o <= 4; o <<= 1) es += __shfl_xor(es, o);
    if (g == 0 && qv) {
        float ls = m + __logf(es);
        float4 o0, o1;
        o0.x = v[0] - ls; o0.y = v[1] - ls; o0.z = v[2] - ls; o0.w = v[3] - ls;
        o1.x = v[4] - ls; o1.y = v[5] - ls; o1.z = v[6] - ls; o1.w = v[7] - ls;
        ((float4*)out)[n * 10 + q * 2]     = o0;
        ((float4*)out)[n * 10 + q * 2 + 1] = o1;
    }
}

extern "C" void kernel_launch(void* const* d_in, const int* in_sizes, int n_in,
                              void* d_out, int out_size, void* d_ws, size_t ws_size,
                              hipStream_t stream) {
    const float* x   = (const float*)d_in[0];
    const int*   ei  = (const int*)d_in[1];   // int32 (JAX x64 disabled)
    const float* W1  = (const float*)d_in[2];
    const float* as1 = (const float*)d_in[3];
    const float* ad1 = (const float*)d_in[4];
    const float* b1  = (const float*)d_in[5];
    const float* W2  = (const float*)d_in[6];
    const float* as2 = (const float*)d_in[7];
    const float* ad2 = (const float*)d_in[8];
    const float* b2  = (const float*)d_in[9];
    float* out = (float*)d_out;

    const int* esrc = ei;
    const int* edst = ei + EE;

    // workspace layout
    __half* h1h = (__half*)d_ws;               // N*128 fp16 (25.6 MB)
    float* es1  = (float*)(h1h + NN * 128);    // N*8
    float* ed1  = es1 + NN * 8;                // N*8
    float* out1 = ed1 + NN * 8;                // N*128 fp32
    __half* h2h = (__half*)(out1 + NN * 128);  // N*40 fp16
    float* es2  = (float*)(h2h + NN * 40);     // N
    float* ed2  = es2 + NN;                    // N
    int* rp     = (int*)(ed2 + NN);            // N+1
    int* cur    = rp + NN + 1;                 // N
    int* bsum   = cur + NN;                    // 64
    int* col    = bsum + 64;                   // ET
    int* cnt    = col + ET;                    // N

    // CSR build (deterministic: scatter + per-node value sort)
    k_init_cnt<<<(NN + 255) / 256, 256, 0, stream>>>(cnt);
    k_hist<<<(EE + 255) / 256, 256, 0, stream>>>(edst, cnt);
    k_scan1<<<NB_SCAN, 256, 0, stream>>>(cnt, rp, bsum);
    k_scan2<<<1, 64, 0, stream>>>(bsum);
    k_scan3<<<(NN + 255) / 256, 256, 0, stream>>>(rp, bsum, cur);
    k_scatter<<<(ET + 255) / 256, 256, 0, stream>>>(esrc, edst, cur, col);
    k_sortcol<<<(NN * 64) / 256, 256, 0, stream>>>(rp, col);

    // layer 1
    k_gemm1<<<NN / 16, 256, 0, stream>>>(x, W1, as1, ad1, h1h, es1, ed1);
    k_agg1<<<(NN * 64) / 256, 256, 0, stream>>>(rp, col, h1h, es1, ed1, b1, out1);

    // layer 2 (gemm2 fused with logits2)
    k_gemm2<<<(NN + 255) / 256, 256, 0, stream>>>(out1, W2, as2, ad2, h2h, es2, ed2);
    k_agg2<<<(NN * 64) / 256, 256, 0, stream>>>(rp, col, h2h, es2, ed2, b2, out);
}

// Round 6
// 418.901 us; speedup vs baseline: 2.0303x; 1.2507x over previous
//
#include <hip/hip_runtime.h>
#include <hip/hip_fp16.h>
#include <math.h>

#define NN 100000
#define EE 1600000
#define ET (EE + NN)
#define NB_SCAN 49    // ceil(NN/2048)
#define BWN 256       // nodes per bucket
#define NBUCK 391     // ceil(NN/BWN)
#define ACHUNK 4096   // edges per bucket-scatter block
#define NAB 416       // ceil(ET/ACHUNK)
#define MAXS 6144     // LDS staging cap (mean 4352, sd 64 -> +28 sigma)

__device__ __forceinline__ float lrelu(float x) { return x > 0.f ? x : 0.2f * x; }

// ---------------- Layer 1 GEMM: h1h (fp16) = x @ W1, plus logits es1/ed1 -----------
__global__ void k_gemm1(const float* __restrict__ x, const float* __restrict__ W1,
                        const float* __restrict__ as1, const float* __restrict__ ad1,
                        __half* __restrict__ h1h, float* __restrict__ es1,
                        float* __restrict__ ed1) {
    __shared__ float xs[16][132];   // +4 pad: kills 4-way bank conflict
    int tid = threadIdx.x;
    int rbase = blockIdx.x * 16;
    for (int j = 0; j < 2; ++j) {
        int lin = tid + j * 256;          // 0..511 -> 512 float4 loads
        int r = lin >> 5, k4 = lin & 31;
        int row = rbase + r;
        float4 v = (row < NN) ? ((const float4*)x)[row * 32 + k4]
                              : make_float4(0.f, 0.f, 0.f, 0.f);
        *(float4*)&xs[r][k4 * 4] = v;
    }
    __syncthreads();
    int c4 = tid & 31;
    int r0 = (tid >> 5) * 2, r1 = r0 + 1;
    float4 a0 = make_float4(0.f, 0.f, 0.f, 0.f);
    float4 a1 = make_float4(0.f, 0.f, 0.f, 0.f);
    const float4* W1v = (const float4*)W1;
    #pragma unroll 8
    for (int k = 0; k < 128; ++k) {
        float4 w = W1v[k * 32 + c4];
        float x0 = xs[r0][k], x1 = xs[r1][k];
        a0.x += x0 * w.x; a0.y += x0 * w.y; a0.z += x0 * w.z; a0.w += x0 * w.w;
        a1.x += x1 * w.x; a1.y += x1 * w.y; a1.z += x1 * w.z; a1.w += x1 * w.w;
    }
    int row0 = rbase + r0, row1 = rbase + r1;
    union { __half2 h[2]; uint2 u; } cv0, cv1;
    cv0.h[0] = __floats2half2_rn(a0.x, a0.y); cv0.h[1] = __floats2half2_rn(a0.z, a0.w);
    cv1.h[0] = __floats2half2_rn(a1.x, a1.y); cv1.h[1] = __floats2half2_rn(a1.z, a1.w);
    if (row0 < NN) ((uint2*)h1h)[row0 * 32 + c4] = cv0.u;
    if (row1 < NN) ((uint2*)h1h)[row1 * 32 + c4] = cv1.u;
    float4 s4 = ((const float4*)as1)[c4], d4 = ((const float4*)ad1)[c4];
    float s0 = a0.x * s4.x + a0.y * s4.y + a0.z * s4.z + a0.w * s4.w;
    float d0 = a0.x * d4.x + a0.y * d4.y + a0.z * d4.z + a0.w * d4.w;
    float s1 = a1.x * s4.x + a1.y * s4.y + a1.z * s4.z + a1.w * s4.w;
    float d1 = a1.x * d4.x + a1.y * d4.y + a1.z * d4.z + a1.w * d4.w;
    s0 += __shfl_xor(s0, 1); s0 += __shfl_xor(s0, 2);
    d0 += __shfl_xor(d0, 1); d0 += __shfl_xor(d0, 2);
    s1 += __shfl_xor(s1, 1); s1 += __shfl_xor(s1, 2);
    d1 += __shfl_xor(d1, 1); d1 += __shfl_xor(d1, 2);
    if ((c4 & 3) == 0) {
        int h = c4 >> 2;
        if (row0 < NN) { es1[row0 * 8 + h] = s0; ed1[row0 * 8 + h] = d0; }
        if (row1 < NN) { es1[row1 * 8 + h] = s1; ed1[row1 * 8 + h] = d1; }
    }
}

// ================= CSR build: two-level bucket sort (write-amp-free) ===============
// Bucket b = dst >> 8 (256 nodes). bedge packs src | (dst&255)<<24 in a u32.

__global__ void k_bhist(const int* __restrict__ dst, int* __restrict__ bcnt) {
    __shared__ int lh[NBUCK];
    int t = threadIdx.x;
    for (int i = t; i < NBUCK; i += 256) lh[i] = 0;
    __syncthreads();
    int c0 = blockIdx.x * ACHUNK;
    #pragma unroll
    for (int i = 0; i < 16; ++i) {
        int e = c0 + t + i * 256;
        if (e < ET) {
            int d = (e < EE) ? dst[e] : e - EE;
            atomicAdd(&lh[d >> 8], 1);
        }
    }
    __syncthreads();
    for (int i = t; i < NBUCK; i += 256) {
        int c = lh[i];
        if (c) atomicAdd(&bcnt[i], c);
    }
}

__global__ void k_bscan(const int* __restrict__ bcnt, int* __restrict__ bbase,
                        int* __restrict__ bcur) {
    __shared__ int sd[256];
    int t = threadIdx.x;
    int i0 = 2 * t, i1 = 2 * t + 1;
    int v0 = (i0 < NBUCK) ? bcnt[i0] : 0;
    int v1 = (i1 < NBUCK) ? bcnt[i1] : 0;
    int s = v0 + v1;
    sd[t] = s;
    __syncthreads();
    for (int off = 1; off < 256; off <<= 1) {
        int xv = (t >= off) ? sd[t - off] : 0;
        __syncthreads();
        sd[t] += xv;
        __syncthreads();
    }
    int excl = sd[t] - s;
    if (i0 <= NBUCK) { bbase[i0] = excl; if (i0 < NBUCK) bcur[i0] = excl; }
    if (i1 <= NBUCK) { bbase[i1] = excl + v0; if (i1 < NBUCK) bcur[i1] = excl + v0; }
}

__global__ void k_bscatter(const int* __restrict__ src, const int* __restrict__ dst,
                           int* __restrict__ bcur, unsigned int* __restrict__ bedge) {
    __shared__ int lh[NBUCK];
    __shared__ int lb[NBUCK];
    int t = threadIdx.x;
    for (int i = t; i < NBUCK; i += 256) lh[i] = 0;
    __syncthreads();
    int c0 = blockIdx.x * ACHUNK;
    unsigned int val[16];
    int bkt[16];
    int rnk[16];
    #pragma unroll
    for (int i = 0; i < 16; ++i) {
        int e = c0 + t + i * 256;
        if (e < ET) {
            int s, d;
            if (e < EE) { s = src[e]; d = dst[e]; } else { s = d = e - EE; }
            int b = d >> 8;
            bkt[i] = b;
            val[i] = (unsigned)s | ((unsigned)(d & 255) << 24);
            rnk[i] = atomicAdd(&lh[b], 1);
        } else bkt[i] = -1;
    }
    __syncthreads();
    for (int i = t; i < NBUCK; i += 256) {
        int c = lh[i];
        lb[i] = c ? atomicAdd(&bcur[i], c) : 0;
    }
    __syncthreads();
    #pragma unroll
    for (int i = 0; i < 16; ++i)
        if (bkt[i] >= 0) bedge[lb[bkt[i]] + rnk[i]] = val[i];
}

// per-node counts (coalesced write; self-loops included via bedge)
__global__ void k_bcnt(const unsigned int* __restrict__ bedge,
                       const int* __restrict__ bbase, int* __restrict__ cnt) {
    __shared__ int lh[BWN];
    int b = blockIdx.x, t = threadIdx.x;
    lh[t] = 0;
    __syncthreads();
    int beg = bbase[b], end = bbase[b + 1];
    for (int e = beg + t; e < end; e += 256) atomicAdd(&lh[bedge[e] >> 24], 1);
    __syncthreads();
    int n = b * BWN + t;
    if (n < NN) cnt[n] = lh[t];
}

__global__ void k_scan1(const int* __restrict__ cnt, int* __restrict__ rp,
                        int* __restrict__ bsum) {
    __shared__ int sd[256];
    int t = threadIdx.x;
    int base = blockIdx.x * 2048 + t * 8;
    int v[8];
    int s = 0;
    #pragma unroll
    for (int j = 0; j < 8; ++j) {
        int i = base + j;
        v[j] = (i < NN) ? cnt[i] : 0;
        s += v[j];
    }
    sd[t] = s;
    __syncthreads();
    for (int off = 1; off < 256; off <<= 1) {
        int xv = (t >= off) ? sd[t - off] : 0;
        __syncthreads();
        sd[t] += xv;
        __syncthreads();
    }
    int excl = sd[t] - s;
    if (t == 255) bsum[blockIdx.x] = sd[255];
    #pragma unroll
    for (int j = 0; j < 8; ++j) {
        int i = base + j;
        if (i < NN) rp[i] = excl;
        excl += v[j];
    }
}

__global__ void k_scan2(int* __restrict__ bsum) {
    if (threadIdx.x == 0 && blockIdx.x == 0) {
        int s = 0;
        for (int i = 0; i < NB_SCAN; ++i) { int c = bsum[i]; bsum[i] = s; s += c; }
    }
}

__global__ void k_scan3(int* __restrict__ rp, const int* __restrict__ bsum) {
    int i = blockIdx.x * 256 + threadIdx.x;
    if (i < NN) rp[i] += bsum[i >> 11];
    if (i == 0) rp[NN] = ET;
}

// place + per-node value sort (determinism) + coalesced col write, all via LDS
__global__ void k_place(const unsigned int* __restrict__ bedge,
                        const int* __restrict__ bbase, const int* __restrict__ rp,
                        int* __restrict__ col) {
    __shared__ int base[BWN + 1];
    __shared__ int lcur[BWN];
    __shared__ int stg[MAXS];
    int b = blockIdx.x, t = threadIdx.x;
    int n0 = b * BWN;
    for (int i = t; i <= BWN; i += 256) {
        int n = n0 + i;
        base[i] = rp[n < NN ? n : NN];
    }
    lcur[t] = 0;
    __syncthreads();
    int beg = bbase[b], end = bbase[b + 1];
    int r0 = base[0];
    int S = base[BWN] - r0;
    int lane = t & 63, w = t >> 6;
    if (S <= MAXS) {
        for (int e = beg + t; e < end; e += 256) {
            unsigned v = bedge[e];
            int i = v >> 24;
            int pos = (base[i] - r0) + atomicAdd(&lcur[i], 1);
            stg[pos] = (int)(v & 0xFFFFFFu);
        }
        __syncthreads();
        for (int i = w; i < BWN; i += 4) {
            int sb = base[i] - r0, d = base[i + 1] - base[i];
            if (d <= 1) continue;
            if (d <= 64) {
                int v = (lane < d) ? stg[sb + lane] : 0x7fffffff;
                #pragma unroll
                for (int k = 2; k <= 64; k <<= 1) {
                    #pragma unroll
                    for (int j = k >> 1; j > 0; j >>= 1) {
                        int other = __shfl_xor(v, j);
                        bool lower = (lane & j) == 0;
                        bool up = (lane & k) == 0;
                        v = (lower == up) ? min(v, other) : max(v, other);
                    }
                }
                if (lane < d) stg[sb + lane] = v;
            } else if (lane == 0) {
                for (int p = sb + 1; p < sb + d; ++p) {
                    int key = stg[p]; int j = p - 1;
                    while (j >= sb && stg[j] > key) { stg[j + 1] = stg[j]; --j; }
                    stg[j + 1] = key;
                }
            }
        }
        __syncthreads();
        for (int j = t; j < S; j += 256) col[r0 + j] = stg[j];
    } else {
        // fallback (statistically unreachable): direct global place + serial sorts
        for (int e = beg + t; e < end; e += 256) {
            unsigned v = bedge[e];
            int i = v >> 24;
            int pos = base[i] + atomicAdd(&lcur[i], 1);
            col[pos] = (int)(v & 0xFFFFFFu);
        }
        __syncthreads();
        if (t < BWN) {
            int sb = base[t], d = base[t + 1] - base[t];
            for (int p = sb + 1; p < sb + d; ++p) {
                int key = col[p]; int j = p - 1;
                while (j >= sb && col[j] > key) { col[j + 1] = col[j]; --j; }
                col[j + 1] = key;
            }
        }
    }
}

// ------- Layer 1 aggregate: wave per node, 8 edges/iter, lane = head q, 16 ch ------
__global__ void k_agg1(const int* __restrict__ rp, const int* __restrict__ col,
                       const __half* __restrict__ h1h, const float* __restrict__ es1,
                       const float* __restrict__ ed1, const float* __restrict__ b1,
                       float* __restrict__ out1) {
    int gid = blockIdx.x * blockDim.x + threadIdx.x;
    int n = gid >> 6, lane = threadIdx.x & 63;
    if (n >= NN) return;
    int g = lane >> 3;
    int q = lane & 7;
    float edn = ed1[n * 8 + q];
    int beg = rp[n], end = rp[n + 1];
    const uint4* h1v = (const uint4*)h1h;
    float acc[16];
    #pragma unroll
    for (int j = 0; j < 16; ++j) acc[j] = 0.f;
    float den = 0.f;
    for (int e0 = beg; e0 < end; e0 += 8) {
        int e = e0 + g;
        if (e < end) {
            int s = col[e];
            float ex = __expf(lrelu(es1[s * 8 + q] + edn));
            den += ex;
            uint4 u0 = h1v[s * 16 + q * 2];
            uint4 u1 = h1v[s * 16 + q * 2 + 1];
            const __half2* hp0 = (const __half2*)&u0;
            const __half2* hp1 = (const __half2*)&u1;
            #pragma unroll
            for (int j = 0; j < 4; ++j) {
                float2 f0 = __half22float2(hp0[j]);
                float2 f1 = __half22float2(hp1[j]);
                acc[j * 2]     += ex * f0.x; acc[j * 2 + 1] += ex * f0.y;
                acc[8 + j * 2] += ex * f1.x; acc[9 + j * 2] += ex * f1.y;
            }
        }
    }
    #pragma unroll
    for (int o = 8; o <= 32; o <<= 1) {
        #pragma unroll
        for (int j = 0; j < 16; ++j) acc[j] += __shfl_xor(acc[j], o);
        den += __shfl_xor(den, o);
    }
    if (g == 0) {
        float inv = 1.f / (den + 1e-16f);
        #pragma unroll
        for (int i = 0; i < 4; ++i) {
            float4 b = ((const float4*)b1)[q * 4 + i];
            float4 o4;
            o4.x = fmaxf(acc[i * 4]     * inv + b.x, 0.f);
            o4.y = fmaxf(acc[i * 4 + 1] * inv + b.y, 0.f);
            o4.z = fmaxf(acc[i * 4 + 2] * inv + b.z, 0.f);
            o4.w = fmaxf(acc[i * 4 + 3] * inv + b.w, 0.f);
            ((float4*)out1)[n * 32 + q * 4 + i] = o4;
        }
    }
}

// ------- Layer 2 GEMM + logits, fused: thread-per-row, 40 acc in VGPRs -------------
__global__ __launch_bounds__(256) void k_gemm2(
        const float* __restrict__ out1, const float* __restrict__ W2,
        const float* __restrict__ as2, const float* __restrict__ ad2,
        __half* __restrict__ h2h, float* __restrict__ es2, float* __restrict__ ed2) {
    __shared__ float xs[32][257];
    int tid = threadIdx.x;
    int rbase = blockIdx.x * 256;
    int row = rbase + tid;
    float acc[40];
    #pragma unroll
    for (int c = 0; c < 40; ++c) acc[c] = 0.f;
    for (int ch = 0; ch < 4; ++ch) {
        __syncthreads();
        #pragma unroll
        for (int i = 0; i < 8; ++i) {
            int idx = tid + i * 256;
            int r = idx >> 3, j4 = idx & 7;
            int rr = rbase + r;
            float4 v = (rr < NN) ? ((const float4*)out1)[rr * 32 + ch * 8 + j4]
                                 : make_float4(0.f, 0.f, 0.f, 0.f);
            xs[j4 * 4 + 0][r] = v.x;
            xs[j4 * 4 + 1][r] = v.y;
            xs[j4 * 4 + 2][r] = v.z;
            xs[j4 * 4 + 3][r] = v.w;
        }
        __syncthreads();
        #pragma unroll 4
        for (int j = 0; j < 32; ++j) {
            float xk = xs[j][tid];
            const float* wrow = W2 + (ch * 32 + j) * 40;
            #pragma unroll
            for (int c = 0; c < 40; ++c) acc[c] += xk * wrow[c];
        }
    }
    if (row < NN) {
        float s = 0.f, d = 0.f;
        #pragma unroll
        for (int c = 0; c < 40; ++c) { s += acc[c] * as2[c]; d += acc[c] * ad2[c]; }
        es2[row] = s;
        ed2[row] = d;
        union { __half2 h[20]; uint4 u[5]; } cv;
        #pragma unroll
        for (int c = 0; c < 20; ++c)
            cv.h[c] = __floats2half2_rn(acc[c * 2], acc[c * 2 + 1]);
        #pragma unroll
        for (int i = 0; i < 5; ++i) ((uint4*)h2h)[row * 5 + i] = cv.u[i];
    }
}

// -- Layer 2 aggregate + log_softmax: wave per node, 8 edges/iter, lane q<5: 8 ch ---
__global__ void k_agg2(const int* __restrict__ rp, const int* __restrict__ col,
                       const __half* __restrict__ h2h, const float* __restrict__ es2,
                       const float* __restrict__ ed2, const float* __restrict__ b2,
                       float* __restrict__ out) {
    int gid = blockIdx.x * blockDim.x + threadIdx.x;
    int n = gid >> 6, lane = threadIdx.x & 63;
    if (n >= NN) return;
    int g = lane >> 3;
    int q = lane & 7;
    bool qv = q < 5;
    float edn = ed2[n];
    int beg = rp[n], end = rp[n + 1];
    const uint4* h2v = (const uint4*)h2h;
    float acc[8];
    #pragma unroll
    for (int j = 0; j < 8; ++j) acc[j] = 0.f;
    float den = 0.f;
    for (int e0 = beg; e0 < end; e0 += 8) {
        int e = e0 + g;
        if (e < end) {
            int s = col[e];
            float ex = __expf(lrelu(es2[s] + edn));
            den += ex;
            if (qv) {
                uint4 u = h2v[s * 5 + q];
                const __half2* hp = (const __half2*)&u;
                #pragma unroll
                for (int j = 0; j < 4; ++j) {
                    float2 f = __half22float2(hp[j]);
                    acc[j * 2]     += ex * f.x;
                    acc[j * 2 + 1] += ex * f.y;
                }
            }
        }
    }
    #pragma unroll
    for (int o = 8; o <= 32; o <<= 1) {
        #pragma unroll
        for (int j = 0; j < 8; ++j) acc[j] += __shfl_xor(acc[j], o);
        den += __shfl_xor(den, o);
    }
    float inv = 1.f / (den + 1e-16f);
    float v[8];
    float m = -INFINITY;
    if (qv) {
        #pragma unroll
        for (int j = 0; j < 8; ++j) {
            v[j] = acc[j] * inv + b2[q * 8 + j];
            m = fmaxf(m, v[j]);
        }
    }
    #pragma unroll
    for (int o = 1; o <= 4; o <<= 1) m = fmaxf(m, __shfl_xor(m, o));
    float es = 0.f;
    if (qv) {
        #pragma unroll
        for (int j = 0; j < 8; ++j) es += __expf(v[j] - m);
    }
    #pragma unroll
    for (int o = 1; o <= 4; o <<= 1) es += __shfl_xor(es, o);
    if (g == 0 && qv) {
        float ls = m + __logf(es);
        float4 o0, o1;
        o0.x = v[0] - ls; o0.y = v[1] - ls; o0.z = v[2] - ls; o0.w = v[3] - ls;
        o1.x = v[4] - ls; o1.y = v[5] - ls; o1.z = v[6] - ls; o1.w = v[7] - ls;
        ((float4*)out)[n * 10 + q * 2]     = o0;
        ((float4*)out)[n * 10 + q * 2 + 1] = o1;
    }
}

extern "C" void kernel_launch(void* const* d_in, const int* in_sizes, int n_in,
                              void* d_out, int out_size, void* d_ws, size_t ws_size,
                              hipStream_t stream) {
    const float* x   = (const float*)d_in[0];
    const int*   ei  = (const int*)d_in[1];   // int32 (JAX x64 disabled)
    const float* W1  = (const float*)d_in[2];
    const float* as1 = (const float*)d_in[3];
    const float* ad1 = (const float*)d_in[4];
    const float* b1  = (const float*)d_in[5];
    const float* W2  = (const float*)d_in[6];
    const float* as2 = (const float*)d_in[7];
    const float* ad2 = (const float*)d_in[8];
    const float* b2  = (const float*)d_in[9];
    float* out = (float*)d_out;

    const int* esrc = ei;
    const int* edst = ei + EE;

    // workspace layout
    __half* h1h = (__half*)d_ws;               // N*128 fp16
    float* es1  = (float*)(h1h + NN * 128);    // N*8
    float* ed1  = es1 + NN * 8;                // N*8
    float* out1 = ed1 + NN * 8;                // N*128 fp32
    __half* h2h = (__half*)(out1 + NN * 128);  // N*40 fp16
    float* es2  = (float*)(h2h + NN * 40);     // N
    float* ed2  = es2 + NN;                    // N
    int* rp     = (int*)(ed2 + NN);            // N+1
    int* bsum   = rp + NN + 1;                 // 64
    int* cnt    = bsum + 64;                   // N
    int* col    = cnt + NN;                    // ET
    int* bcnt   = col + ET;                    // NBUCK
    int* bbase  = bcnt + NBUCK;                // NBUCK+1
    int* bcur   = bbase + NBUCK + 1;           // NBUCK
    unsigned int* bedge = (unsigned int*)(bcur + NBUCK);  // ET

    // CSR build: bucket sort -> per-node counts -> scan -> place(+sort in LDS)
    hipMemsetAsync(bcnt, 0, NBUCK * sizeof(int), stream);
    k_bhist<<<NAB, 256, 0, stream>>>(edst, bcnt);
    k_bscan<<<1, 256, 0, stream>>>(bcnt, bbase, bcur);
    k_bscatter<<<NAB, 256, 0, stream>>>(esrc, edst, bcur, bedge);
    k_bcnt<<<NBUCK, 256, 0, stream>>>(bedge, bbase, cnt);
    k_scan1<<<NB_SCAN, 256, 0, stream>>>(cnt, rp, bsum);
    k_scan2<<<1, 64, 0, stream>>>(bsum);
    k_scan3<<<(NN + 255) / 256, 256, 0, stream>>>(rp, bsum);
    k_place<<<NBUCK, 256, 0, stream>>>(bedge, bbase, rp, col);

    // layer 1
    k_gemm1<<<NN / 16, 256, 0, stream>>>(x, W1, as1, ad1, h1h, es1, ed1);
    k_agg1<<<(NN * 64) / 256, 256, 0, stream>>>(rp, col, h1h, es1, ed1, b1, out1);

    // layer 2 (gemm2 fused with logits2)
    k_gemm2<<<(NN + 255) / 256, 256, 0, stream>>>(out1, W2, as2, ad2, h2h, es2, ed2);
    k_agg2<<<(NN * 64) / 256, 256, 0, stream>>>(rp, col, h2h, es2, ed2, b2, out);
}

// Round 7
// 376.662 us; speedup vs baseline: 2.2580x; 1.1121x over previous
//
#include <hip/hip_runtime.h>
#include <hip/hip_fp16.h>
#include <math.h>

#define NN 100000
#define EE 1600000
#define ET (EE + NN)
#define NB_SCAN 49    // ceil(NN/2048)
#define BWN 256       // nodes per bucket
#define NBUCK 391     // ceil(NN/BWN)
#define ACHUNK 4096   // edges per bucket-scatter block
#define NAB 416       // ceil(ET/ACHUNK)
#define MAXS 6144     // LDS staging cap (mean 4352, sd 64 -> +28 sigma)

typedef _Float16 f16x8 __attribute__((ext_vector_type(8)));
typedef float f32x4 __attribute__((ext_vector_type(4)));

__device__ __forceinline__ float lrelu(float x) { return x > 0.f ? x : 0.2f * x; }

// ---- W1 fragment pack: plane 0 = fp16(W1), plane 1 = fp16 residual ----------------
// flat idx = plane*16384 + ct*2048 + k0*512 + lane*8 + j
// value = W1[(k0*32 + (lane>>4)*8 + j)*128 + ct*16 + (lane&15)]
__global__ void k_w1pack(const float* __restrict__ W1, __half* __restrict__ w1p) {
    int idx = blockIdx.x * 256 + threadIdx.x;   // 0..32767
    int j = idx & 7, lane = (idx >> 3) & 63, k0 = (idx >> 9) & 3;
    int ct = (idx >> 11) & 7, plane = idx >> 14;
    int k = k0 * 32 + (lane >> 4) * 8 + j;
    int c = ct * 16 + (lane & 15);
    float w = W1[k * 128 + c];
    _Float16 wh = (_Float16)w;
    _Float16 v = plane ? (_Float16)(w - (float)wh) : wh;
    w1p[idx] = *(__half*)&v;
}

// ---- Layer 1 GEMM via MFMA (error-compensated fp16): h1h + logits es1/ed1 ---------
// block 256 = 4 waves; wave computes 16 rows x 128 cols; 3-term split keeps fp32 acc.
__global__ __launch_bounds__(256) void k_gemm1(
        const float* __restrict__ x, const __half* __restrict__ w1p,
        const float* __restrict__ as1, const float* __restrict__ ad1,
        __half* __restrict__ h1h, float* __restrict__ es1, float* __restrict__ ed1) {
    int tid = threadIdx.x;
    int w = tid >> 6, lane = tid & 63;
    int rb = blockIdx.x * 64 + w * 16;
    int l15 = lane & 15, rg = lane >> 4;

    // A fragments: row = rb + (lane&15), k = k0*32 + (lane>>4)*8 + j
    int arow = rb + l15;
    bool aok = arow < NN;
    const float4* x4 = (const float4*)x;
    f16x8 ah[4], ar[4];
    #pragma unroll
    for (int k0 = 0; k0 < 4; ++k0) {
        float4 p0 = make_float4(0.f, 0.f, 0.f, 0.f), p1 = p0;
        if (aok) {
            int fi = arow * 32 + k0 * 8 + rg * 2;
            p0 = x4[fi];
            p1 = x4[fi + 1];
        }
        float pv[8] = {p0.x, p0.y, p0.z, p0.w, p1.x, p1.y, p1.z, p1.w};
        #pragma unroll
        for (int j = 0; j < 8; ++j) {
            _Float16 h = (_Float16)pv[j];
            ah[k0][j] = h;
            ar[k0][j] = (_Float16)(pv[j] - (float)h);
        }
    }

    const f16x8* w1f = (const f16x8*)w1p;   // [plane:2][ct:8][k0:4][lane:64]
    f32x4 acc[8];
    #pragma unroll
    for (int ct = 0; ct < 8; ++ct) acc[ct] = (f32x4){0.f, 0.f, 0.f, 0.f};
    #pragma unroll
    for (int ct = 0; ct < 8; ++ct) {
        #pragma unroll
        for (int k0 = 0; k0 < 4; ++k0) {
            f16x8 bh = w1f[(ct * 4 + k0) * 64 + lane];
            f16x8 br = w1f[2048 + (ct * 4 + k0) * 64 + lane];
            acc[ct] = __builtin_amdgcn_mfma_f32_16x16x32_f16(ah[k0], bh, acc[ct], 0, 0, 0);
            acc[ct] = __builtin_amdgcn_mfma_f32_16x16x32_f16(ar[k0], bh, acc[ct], 0, 0, 0);
            acc[ct] = __builtin_amdgcn_mfma_f32_16x16x32_f16(ah[k0], br, acc[ct], 0, 0, 0);
        }
    }

    // epilogue: C col = lane&15, row = rb + (lane>>4)*4 + r  (head == ct)
    #pragma unroll
    for (int ct = 0; ct < 8; ++ct) {
        float as_c = as1[ct * 16 + l15];
        float ad_c = ad1[ct * 16 + l15];
        #pragma unroll
        for (int r = 0; r < 4; ++r) {
            int row = rb + rg * 4 + r;
            float v = acc[ct][r];
            if (row < NN) h1h[row * 128 + ct * 16 + l15] = __float2half_rn(v);
            float s = v * as_c, d = v * ad_c;
            s += __shfl_xor(s, 1); s += __shfl_xor(s, 2);
            s += __shfl_xor(s, 4); s += __shfl_xor(s, 8);
            d += __shfl_xor(d, 1); d += __shfl_xor(d, 2);
            d += __shfl_xor(d, 4); d += __shfl_xor(d, 8);
            if (l15 == 0 && row < NN) { es1[row * 8 + ct] = s; ed1[row * 8 + ct] = d; }
        }
    }
}

// ================= CSR build: two-level bucket sort (write-amp-free) ===============
__global__ void k_bhist(const int* __restrict__ dst, int* __restrict__ bcnt) {
    __shared__ int lh[NBUCK];
    int t = threadIdx.x;
    for (int i = t; i < NBUCK; i += 256) lh[i] = 0;
    __syncthreads();
    int c0 = blockIdx.x * ACHUNK;
    #pragma unroll
    for (int i = 0; i < 16; ++i) {
        int e = c0 + t + i * 256;
        if (e < ET) {
            int d = (e < EE) ? dst[e] : e - EE;
            atomicAdd(&lh[d >> 8], 1);
        }
    }
    __syncthreads();
    for (int i = t; i < NBUCK; i += 256) {
        int c = lh[i];
        if (c) atomicAdd(&bcnt[i], c);
    }
}

__global__ void k_bscan(const int* __restrict__ bcnt, int* __restrict__ bbase,
                        int* __restrict__ bcur) {
    __shared__ int sd[256];
    int t = threadIdx.x;
    int i0 = 2 * t, i1 = 2 * t + 1;
    int v0 = (i0 < NBUCK) ? bcnt[i0] : 0;
    int v1 = (i1 < NBUCK) ? bcnt[i1] : 0;
    int s = v0 + v1;
    sd[t] = s;
    __syncthreads();
    for (int off = 1; off < 256; off <<= 1) {
        int xv = (t >= off) ? sd[t - off] : 0;
        __syncthreads();
        sd[t] += xv;
        __syncthreads();
    }
    int excl = sd[t] - s;
    if (i0 <= NBUCK) { bbase[i0] = excl; if (i0 < NBUCK) bcur[i0] = excl; }
    if (i1 <= NBUCK) { bbase[i1] = excl + v0; if (i1 < NBUCK) bcur[i1] = excl + v0; }
}

__global__ void k_bscatter(const int* __restrict__ src, const int* __restrict__ dst,
                           int* __restrict__ bcur, unsigned int* __restrict__ bedge) {
    __shared__ int lh[NBUCK];
    __shared__ int lb[NBUCK];
    int t = threadIdx.x;
    for (int i = t; i < NBUCK; i += 256) lh[i] = 0;
    __syncthreads();
    int c0 = blockIdx.x * ACHUNK;
    unsigned int val[16];
    int bkt[16];
    int rnk[16];
    #pragma unroll
    for (int i = 0; i < 16; ++i) {
        int e = c0 + t + i * 256;
        if (e < ET) {
            int s, d;
            if (e < EE) { s = src[e]; d = dst[e]; } else { s = d = e - EE; }
            int b = d >> 8;
            bkt[i] = b;
            val[i] = (unsigned)s | ((unsigned)(d & 255) << 24);
            rnk[i] = atomicAdd(&lh[b], 1);
        } else bkt[i] = -1;
    }
    __syncthreads();
    for (int i = t; i < NBUCK; i += 256) {
        int c = lh[i];
        lb[i] = c ? atomicAdd(&bcur[i], c) : 0;
    }
    __syncthreads();
    #pragma unroll
    for (int i = 0; i < 16; ++i)
        if (bkt[i] >= 0) bedge[lb[bkt[i]] + rnk[i]] = val[i];
}

__global__ void k_bcnt(const unsigned int* __restrict__ bedge,
                       const int* __restrict__ bbase, int* __restrict__ cnt) {
    __shared__ int lh[BWN];
    int b = blockIdx.x, t = threadIdx.x;
    lh[t] = 0;
    __syncthreads();
    int beg = bbase[b], end = bbase[b + 1];
    for (int e = beg + t; e < end; e += 256) atomicAdd(&lh[bedge[e] >> 24], 1);
    __syncthreads();
    int n = b * BWN + t;
    if (n < NN) cnt[n] = lh[t];
}

__global__ void k_scan1(const int* __restrict__ cnt, int* __restrict__ rp,
                        int* __restrict__ bsum) {
    __shared__ int sd[256];
    int t = threadIdx.x;
    int base = blockIdx.x * 2048 + t * 8;
    int v[8];
    int s = 0;
    #pragma unroll
    for (int j = 0; j < 8; ++j) {
        int i = base + j;
        v[j] = (i < NN) ? cnt[i] : 0;
        s += v[j];
    }
    sd[t] = s;
    __syncthreads();
    for (int off = 1; off < 256; off <<= 1) {
        int xv = (t >= off) ? sd[t - off] : 0;
        __syncthreads();
        sd[t] += xv;
        __syncthreads();
    }
    int excl = sd[t] - s;
    if (t == 255) bsum[blockIdx.x] = sd[255];
    #pragma unroll
    for (int j = 0; j < 8; ++j) {
        int i = base + j;
        if (i < NN) rp[i] = excl;
        excl += v[j];
    }
}

__global__ void k_scan2(int* __restrict__ bsum) {
    if (threadIdx.x == 0 && blockIdx.x == 0) {
        int s = 0;
        for (int i = 0; i < NB_SCAN; ++i) { int c = bsum[i]; bsum[i] = s; s += c; }
    }
}

__global__ void k_scan3(int* __restrict__ rp, const int* __restrict__ bsum) {
    int i = blockIdx.x * 256 + threadIdx.x;
    if (i < NN) rp[i] += bsum[i >> 11];
    if (i == 0) rp[NN] = ET;
}

__global__ void k_place(const unsigned int* __restrict__ bedge,
                        const int* __restrict__ bbase, const int* __restrict__ rp,
                        int* __restrict__ col) {
    __shared__ int base[BWN + 1];
    __shared__ int lcur[BWN];
    __shared__ int stg[MAXS];
    int b = blockIdx.x, t = threadIdx.x;
    int n0 = b * BWN;
    for (int i = t; i <= BWN; i += 256) {
        int n = n0 + i;
        base[i] = rp[n < NN ? n : NN];
    }
    lcur[t] = 0;
    __syncthreads();
    int beg = bbase[b], end = bbase[b + 1];
    int r0 = base[0];
    int S = base[BWN] - r0;
    int lane = t & 63, w = t >> 6;
    if (S <= MAXS) {
        for (int e = beg + t; e < end; e += 256) {
            unsigned v = bedge[e];
            int i = v >> 24;
            int pos = (base[i] - r0) + atomicAdd(&lcur[i], 1);
            stg[pos] = (int)(v & 0xFFFFFFu);
        }
        __syncthreads();
        for (int i = w; i < BWN; i += 4) {
            int sb = base[i] - r0, d = base[i + 1] - base[i];
            if (d <= 1) continue;
            if (d <= 64) {
                int v = (lane < d) ? stg[sb + lane] : 0x7fffffff;
                #pragma unroll
                for (int k = 2; k <= 64; k <<= 1) {
                    #pragma unroll
                    for (int j = k >> 1; j > 0; j >>= 1) {
                        int other = __shfl_xor(v, j);
                        bool lower = (lane & j) == 0;
                        bool up = (lane & k) == 0;
                        v = (lower == up) ? min(v, other) : max(v, other);
                    }
                }
                if (lane < d) stg[sb + lane] = v;
            } else if (lane == 0) {
                for (int p = sb + 1; p < sb + d; ++p) {
                    int key = stg[p]; int j = p - 1;
                    while (j >= sb && stg[j] > key) { stg[j + 1] = stg[j]; --j; }
                    stg[j + 1] = key;
                }
            }
        }
        __syncthreads();
        for (int j = t; j < S; j += 256) col[r0 + j] = stg[j];
    } else {
        for (int e = beg + t; e < end; e += 256) {
            unsigned v = bedge[e];
            int i = v >> 24;
            int pos = base[i] + atomicAdd(&lcur[i], 1);
            col[pos] = (int)(v & 0xFFFFFFu);
        }
        __syncthreads();
        if (t < BWN) {
            int sb = base[t], d = base[t + 1] - base[t];
            for (int p = sb + 1; p < sb + d; ++p) {
                int key = col[p]; int j = p - 1;
                while (j >= sb && col[j] > key) { col[j + 1] = col[j]; --j; }
                col[j + 1] = key;
            }
        }
    }
}

// ------- Layer 1 aggregate: wave per node, 8 edges/iter, lane = head q, 16 ch ------
__global__ void k_agg1(const int* __restrict__ rp, const int* __restrict__ col,
                       const __half* __restrict__ h1h, const float* __restrict__ es1,
                       const float* __restrict__ ed1, const float* __restrict__ b1,
                       float* __restrict__ out1) {
    int gid = blockIdx.x * blockDim.x + threadIdx.x;
    int n = gid >> 6, lane = threadIdx.x & 63;
    if (n >= NN) return;
    int g = lane >> 3;
    int q = lane & 7;
    float edn = ed1[n * 8 + q];
    int beg = rp[n], end = rp[n + 1];
    const uint4* h1v = (const uint4*)h1h;
    float acc[16];
    #pragma unroll
    for (int j = 0; j < 16; ++j) acc[j] = 0.f;
    float den = 0.f;
    for (int e0 = beg; e0 < end; e0 += 8) {
        int e = e0 + g;
        if (e < end) {
            int s = col[e];
            float ex = __expf(lrelu(es1[s * 8 + q] + edn));
            den += ex;
            uint4 u0 = h1v[s * 16 + q * 2];
            uint4 u1 = h1v[s * 16 + q * 2 + 1];
            const __half2* hp0 = (const __half2*)&u0;
            const __half2* hp1 = (const __half2*)&u1;
            #pragma unroll
            for (int j = 0; j < 4; ++j) {
                float2 f0 = __half22float2(hp0[j]);
                float2 f1 = __half22float2(hp1[j]);
                acc[j * 2]     += ex * f0.x; acc[j * 2 + 1] += ex * f0.y;
                acc[8 + j * 2] += ex * f1.x; acc[9 + j * 2] += ex * f1.y;
            }
        }
    }
    #pragma unroll
    for (int o = 8; o <= 32; o <<= 1) {
        #pragma unroll
        for (int j = 0; j < 16; ++j) acc[j] += __shfl_xor(acc[j], o);
        den += __shfl_xor(den, o);
    }
    if (g == 0) {
        float inv = 1.f / (den + 1e-16f);
        #pragma unroll
        for (int i = 0; i < 4; ++i) {
            float4 b = ((const float4*)b1)[q * 4 + i];
            float4 o4;
            o4.x = fmaxf(acc[i * 4]     * inv + b.x, 0.f);
            o4.y = fmaxf(acc[i * 4 + 1] * inv + b.y, 0.f);
            o4.z = fmaxf(acc[i * 4 + 2] * inv + b.z, 0.f);
            o4.w = fmaxf(acc[i * 4 + 3] * inv + b.w, 0.f);
            ((float4*)out1)[n * 32 + q * 4 + i] = o4;
        }
    }
}

// ------- Layer 2 GEMM + logits, fused: thread-per-row, 40 acc in VGPRs -------------
__global__ __launch_bounds__(256) void k_gemm2(
        const float* __restrict__ out1, const float* __restrict__ W2,
        const float* __restrict__ as2, const float* __restrict__ ad2,
        __half* __restrict__ h2h, float* __restrict__ es2, float* __restrict__ ed2) {
    __shared__ float xs[32][257];
    int tid = threadIdx.x;
    int rbase = blockIdx.x * 256;
    int row = rbase + tid;
    float acc[40];
    #pragma unroll
    for (int c = 0; c < 40; ++c) acc[c] = 0.f;
    for (int ch = 0; ch < 4; ++ch) {
        __syncthreads();
        #pragma unroll
        for (int i = 0; i < 8; ++i) {
            int idx = tid + i * 256;
            int r = idx >> 3, j4 = idx & 7;
            int rr = rbase + r;
            float4 v = (rr < NN) ? ((const float4*)out1)[rr * 32 + ch * 8 + j4]
                                 : make_float4(0.f, 0.f, 0.f, 0.f);
            xs[j4 * 4 + 0][r] = v.x;
            xs[j4 * 4 + 1][r] = v.y;
            xs[j4 * 4 + 2][r] = v.z;
            xs[j4 * 4 + 3][r] = v.w;
        }
        __syncthreads();
        #pragma unroll 4
        for (int j = 0; j < 32; ++j) {
            float xk = xs[j][tid];
            const float* wrow = W2 + (ch * 32 + j) * 40;
            #pragma unroll
            for (int c = 0; c < 40; ++c) acc[c] += xk * wrow[c];
        }
    }
    if (row < NN) {
        float s = 0.f, d = 0.f;
        #pragma unroll
        for (int c = 0; c < 40; ++c) { s += acc[c] * as2[c]; d += acc[c] * ad2[c]; }
        es2[row] = s;
        ed2[row] = d;
        union { __half2 h[20]; uint4 u[5]; } cv;
        #pragma unroll
        for (int c = 0; c < 20; ++c)
            cv.h[c] = __floats2half2_rn(acc[c * 2], acc[c * 2 + 1]);
        #pragma unroll
        for (int i = 0; i < 5; ++i) ((uint4*)h2h)[row * 5 + i] = cv.u[i];
    }
}

// -- Layer 2 aggregate + log_softmax: wave per node, 8 edges/iter, lane q<5: 8 ch ---
__global__ void k_agg2(const int* __restrict__ rp, const int* __restrict__ col,
                       const __half* __restrict__ h2h, const float* __restrict__ es2,
                       const float* __restrict__ ed2, const float* __restrict__ b2,
                       float* __restrict__ out) {
    int gid = blockIdx.x * blockDim.x + threadIdx.x;
    int n = gid >> 6, lane = threadIdx.x & 63;
    if (n >= NN) return;
    int g = lane >> 3;
    int q = lane & 7;
    bool qv = q < 5;
    float edn = ed2[n];
    int beg = rp[n], end = rp[n + 1];
    const uint4* h2v = (const uint4*)h2h;
    float acc[8];
    #pragma unroll
    for (int j = 0; j < 8; ++j) acc[j] = 0.f;
    float den = 0.f;
    for (int e0 = beg; e0 < end; e0 += 8) {
        int e = e0 + g;
        if (e < end) {
            int s = col[e];
            float ex = __expf(lrelu(es2[s] + edn));
            den += ex;
            if (qv) {
                uint4 u = h2v[s * 5 + q];
                const __half2* hp = (const __half2*)&u;
                #pragma unroll
                for (int j = 0; j < 4; ++j) {
                    float2 f = __half22float2(hp[j]);
                    acc[j * 2]     += ex * f.x;
                    acc[j * 2 + 1] += ex * f.y;
                }
            }
        }
    }
    #pragma unroll
    for (int o = 8; o <= 32; o <<= 1) {
        #pragma unroll
        for (int j = 0; j < 8; ++j) acc[j] += __shfl_xor(acc[j], o);
        den += __shfl_xor(den, o);
    }
    float inv = 1.f / (den + 1e-16f);
    float v[8];
    float m = -INFINITY;
    if (qv) {
        #pragma unroll
        for (int j = 0; j < 8; ++j) {
            v[j] = acc[j] * inv + b2[q * 8 + j];
            m = fmaxf(m, v[j]);
        }
    }
    #pragma unroll
    for (int o = 1; o <= 4; o <<= 1) m = fmaxf(m, __shfl_xor(m, o));
    float es = 0.f;
    if (qv) {
        #pragma unroll
        for (int j = 0; j < 8; ++j) es += __expf(v[j] - m);
    }
    #pragma unroll
    for (int o = 1; o <= 4; o <<= 1) es += __shfl_xor(es, o);
    if (g == 0 && qv) {
        float ls = m + __logf(es);
        float4 o0, o1;
        o0.x = v[0] - ls; o0.y = v[1] - ls; o0.z = v[2] - ls; o0.w = v[3] - ls;
        o1.x = v[4] - ls; o1.y = v[5] - ls; o1.z = v[6] - ls; o1.w = v[7] - ls;
        ((float4*)out)[n * 10 + q * 2]     = o0;
        ((float4*)out)[n * 10 + q * 2 + 1] = o1;
    }
}

extern "C" void kernel_launch(void* const* d_in, const int* in_sizes, int n_in,
                              void* d_out, int out_size, void* d_ws, size_t ws_size,
                              hipStream_t stream) {
    const float* x   = (const float*)d_in[0];
    const int*   ei  = (const int*)d_in[1];   // int32 (JAX x64 disabled)
    const float* W1  = (const float*)d_in[2];
    const float* as1 = (const float*)d_in[3];
    const float* ad1 = (const float*)d_in[4];
    const float* b1  = (const float*)d_in[5];
    const float* W2  = (const float*)d_in[6];
    const float* as2 = (const float*)d_in[7];
    const float* ad2 = (const float*)d_in[8];
    const float* b2  = (const float*)d_in[9];
    float* out = (float*)d_out;

    const int* esrc = ei;
    const int* edst = ei + EE;

    // workspace layout
    __half* h1h = (__half*)d_ws;               // N*128 fp16
    float* es1  = (float*)(h1h + NN * 128);    // N*8
    float* ed1  = es1 + NN * 8;                // N*8
    float* out1 = ed1 + NN * 8;                // N*128 fp32
    __half* h2h = (__half*)(out1 + NN * 128);  // N*40 fp16
    float* es2  = (float*)(h2h + NN * 40);     // N
    float* ed2  = es2 + NN;                    // N
    int* rp     = (int*)(ed2 + NN);            // N+1
    int* bsum   = rp + NN + 1;                 // 64
    int* cnt    = bsum + 64;                   // N
    int* col    = cnt + NN;                    // ET
    int* bcnt   = col + ET;                    // NBUCK
    int* bbase  = bcnt + NBUCK;                // NBUCK+1
    int* bcur   = bbase + NBUCK + 1;           // NBUCK
    unsigned int* bedge = (unsigned int*)(bcur + NBUCK);  // ET
    __half* w1p = (__half*)(bedge + ET);       // 32768 fp16 (64 KB)

    // CSR build: bucket sort -> per-node counts -> scan -> place(+sort in LDS)
    hipMemsetAsync(bcnt, 0, NBUCK * sizeof(int), stream);
    k_bhist<<<NAB, 256, 0, stream>>>(edst, bcnt);
    k_bscan<<<1, 256, 0, stream>>>(bcnt, bbase, bcur);
    k_bscatter<<<NAB, 256, 0, stream>>>(esrc, edst, bcur, bedge);
    k_bcnt<<<NBUCK, 256, 0, stream>>>(bedge, bbase, cnt);
    k_scan1<<<NB_SCAN, 256, 0, stream>>>(cnt, rp, bsum);
    k_scan2<<<1, 64, 0, stream>>>(bsum);
    k_scan3<<<(NN + 255) / 256, 256, 0, stream>>>(rp, bsum);
    k_place<<<NBUCK, 256, 0, stream>>>(bedge, bbase, rp, col);

    // layer 1 (MFMA gemm)
    k_w1pack<<<128, 256, 0, stream>>>(W1, w1p);
    k_gemm1<<<(NN + 63) / 64, 256, 0, stream>>>(x, w1p, as1, ad1, h1h, es1, ed1);
    k_agg1<<<(NN * 64) / 256, 256, 0, stream>>>(rp, col, h1h, es1, ed1, b1, out1);

    // layer 2 (gemm2 fused with logits2)
    k_gemm2<<<(NN + 255) / 256, 256, 0, stream>>>(out1, W2, as2, ad2, h2h, es2, ed2);
    k_agg2<<<(NN * 64) / 256, 256, 0, stream>>>(rp, col, h2h, es2, ed2, b2, out);
}

// Round 8
// 365.557 us; speedup vs baseline: 2.3265x; 1.0304x over previous
//
#include <hip/hip_runtime.h>
#include <hip/hip_fp16.h>
#include <math.h>

#define NN 100000
#define EE 1600000
#define ET (EE + NN)
#define NB_SCAN 49    // ceil(NN/2048)
#define BWN 256       // nodes per bucket
#define NBUCK 391     // ceil(NN/BWN)
#define ACHUNK 4096   // edges per bucket-scatter block
#define NAB 416       // ceil(ET/ACHUNK)
#define MAXS 6144     // LDS staging cap (mean 4352, sd 64 -> +28 sigma)

typedef _Float16 f16x8 __attribute__((ext_vector_type(8)));
typedef float f32x4 __attribute__((ext_vector_type(4)));

__device__ __forceinline__ float lrelu(float x) { return x > 0.f ? x : 0.2f * x; }

// ---- W1 fragment pack: plane 0 = fp16(W1), plane 1 = fp16 residual ----------------
// flat idx = plane*16384 + ct*2048 + k0*512 + lane*8 + j
// value = W1[(k0*32 + (lane>>4)*8 + j)*128 + ct*16 + (lane&15)]
__global__ void k_w1pack(const float* __restrict__ W1, __half* __restrict__ w1p) {
    int idx = blockIdx.x * 256 + threadIdx.x;   // 0..32767
    int j = idx & 7, lane = (idx >> 3) & 63, k0 = (idx >> 9) & 3;
    int ct = (idx >> 11) & 7, plane = idx >> 14;
    int k = k0 * 32 + (lane >> 4) * 8 + j;
    int c = ct * 16 + (lane & 15);
    float w = W1[k * 128 + c];
    _Float16 wh = (_Float16)w;
    _Float16 v = plane ? (_Float16)(w - (float)wh) : wh;
    w1p[idx] = *(__half*)&v;
}

// ---- Layer 1 GEMM via MFMA (error-compensated fp16): h1h + logits es1/ed1 ---------
// OPERAND-SWAPPED: mfma(W_frag, x_frag) -> D col = node, row = channel.
// Each lane then holds 4 consecutive channels of one node -> 8B stores, cheap logits.
__global__ __launch_bounds__(256) void k_gemm1(
        const float* __restrict__ x, const __half* __restrict__ w1p,
        const float* __restrict__ as1, const float* __restrict__ ad1,
        __half* __restrict__ h1h, float* __restrict__ es1, float* __restrict__ ed1) {
    int tid = threadIdx.x;
    int w = tid >> 6, lane = tid & 63;
    int rb = blockIdx.x * 64 + w * 16;
    int l15 = lane & 15, rg = lane >> 4;

    // x fragment (used as MFMA B operand): col j = lane&15 -> node rb+l15,
    // k = (lane>>4)*8 + j within each k0 chunk of 32.
    int arow = rb + l15;
    bool aok = arow < NN;
    const float4* x4 = (const float4*)x;
    f16x8 ah[4], ar[4];
    #pragma unroll
    for (int k0 = 0; k0 < 4; ++k0) {
        float4 p0 = make_float4(0.f, 0.f, 0.f, 0.f), p1 = p0;
        if (aok) {
            int fi = arow * 32 + k0 * 8 + rg * 2;
            p0 = x4[fi];
            p1 = x4[fi + 1];
        }
        float pv[8] = {p0.x, p0.y, p0.z, p0.w, p1.x, p1.y, p1.z, p1.w};
        #pragma unroll
        for (int j = 0; j < 8; ++j) {
            _Float16 h = (_Float16)pv[j];
            ah[k0][j] = h;
            ar[k0][j] = (_Float16)(pv[j] - (float)h);
        }
    }

    const f16x8* w1f = (const f16x8*)w1p;   // [plane:2][ct:8][k0:4][lane:64]
    f32x4 acc[8];
    #pragma unroll
    for (int ct = 0; ct < 8; ++ct) acc[ct] = (f32x4){0.f, 0.f, 0.f, 0.f};
    #pragma unroll
    for (int ct = 0; ct < 8; ++ct) {
        #pragma unroll
        for (int k0 = 0; k0 < 4; ++k0) {
            f16x8 bh = w1f[(ct * 4 + k0) * 64 + lane];
            f16x8 br = w1f[2048 + (ct * 4 + k0) * 64 + lane];
            acc[ct] = __builtin_amdgcn_mfma_f32_16x16x32_f16(bh, ah[k0], acc[ct], 0, 0, 0);
            acc[ct] = __builtin_amdgcn_mfma_f32_16x16x32_f16(bh, ar[k0], acc[ct], 0, 0, 0);
            acc[ct] = __builtin_amdgcn_mfma_f32_16x16x32_f16(br, ah[k0], acc[ct], 0, 0, 0);
        }
    }

    // epilogue: lane -> node rb+l15; acc[ct][r] = h1[node][ct*16 + rg*4 + r]
    int row = rb + l15;
    bool rok = row < NN;
    float es_p[2] = {0.f, 0.f};   // staging for nothing; per-ct handled below
    #pragma unroll
    for (int ct = 0; ct < 8; ++ct) {
        if (rok) {
            union { __half2 h[2]; uint2 u; } cv;
            cv.h[0] = __floats2half2_rn(acc[ct][0], acc[ct][1]);
            cv.h[1] = __floats2half2_rn(acc[ct][2], acc[ct][3]);
            *(uint2*)&h1h[row * 128 + ct * 16 + rg * 4] = cv.u;
        }
        float4 a4 = ((const float4*)as1)[ct * 4 + rg];
        float4 d4 = ((const float4*)ad1)[ct * 4 + rg];
        float s = acc[ct][0] * a4.x + acc[ct][1] * a4.y + acc[ct][2] * a4.z + acc[ct][3] * a4.w;
        float d = acc[ct][0] * d4.x + acc[ct][1] * d4.y + acc[ct][2] * d4.z + acc[ct][3] * d4.w;
        s += __shfl_xor(s, 16); s += __shfl_xor(s, 32);
        d += __shfl_xor(d, 16); d += __shfl_xor(d, 32);
        if (rg == 0 && rok) { es1[row * 8 + ct] = s; ed1[row * 8 + ct] = d; }
    }
    (void)es_p;
}

// ================= CSR build: two-level bucket sort (write-amp-free) ===============
__global__ void k_bhist(const int* __restrict__ dst, int* __restrict__ bcnt) {
    __shared__ int lh[NBUCK];
    int t = threadIdx.x;
    for (int i = t; i < NBUCK; i += 256) lh[i] = 0;
    __syncthreads();
    int c0 = blockIdx.x * ACHUNK;
    #pragma unroll
    for (int i = 0; i < 16; ++i) {
        int e = c0 + t + i * 256;
        if (e < ET) {
            int d = (e < EE) ? dst[e] : e - EE;
            atomicAdd(&lh[d >> 8], 1);
        }
    }
    __syncthreads();
    for (int i = t; i < NBUCK; i += 256) {
        int c = lh[i];
        if (c) atomicAdd(&bcnt[i], c);
    }
}

__global__ void k_bscan(const int* __restrict__ bcnt, int* __restrict__ bbase,
                        int* __restrict__ bcur) {
    __shared__ int sd[256];
    int t = threadIdx.x;
    int i0 = 2 * t, i1 = 2 * t + 1;
    int v0 = (i0 < NBUCK) ? bcnt[i0] : 0;
    int v1 = (i1 < NBUCK) ? bcnt[i1] : 0;
    int s = v0 + v1;
    sd[t] = s;
    __syncthreads();
    for (int off = 1; off < 256; off <<= 1) {
        int xv = (t >= off) ? sd[t - off] : 0;
        __syncthreads();
        sd[t] += xv;
        __syncthreads();
    }
    int excl = sd[t] - s;
    if (i0 <= NBUCK) { bbase[i0] = excl; if (i0 < NBUCK) bcur[i0] = excl; }
    if (i1 <= NBUCK) { bbase[i1] = excl + v0; if (i1 < NBUCK) bcur[i1] = excl + v0; }
}

__global__ void k_bscatter(const int* __restrict__ src, const int* __restrict__ dst,
                           int* __restrict__ bcur, unsigned int* __restrict__ bedge) {
    __shared__ int lh[NBUCK];
    __shared__ int lb[NBUCK];
    int t = threadIdx.x;
    for (int i = t; i < NBUCK; i += 256) lh[i] = 0;
    __syncthreads();
    int c0 = blockIdx.x * ACHUNK;
    unsigned int val[16];
    int bkt[16];
    int rnk[16];
    #pragma unroll
    for (int i = 0; i < 16; ++i) {
        int e = c0 + t + i * 256;
        if (e < ET) {
            int s, d;
            if (e < EE) { s = src[e]; d = dst[e]; } else { s = d = e - EE; }
            int b = d >> 8;
            bkt[i] = b;
            val[i] = (unsigned)s | ((unsigned)(d & 255) << 24);
            rnk[i] = atomicAdd(&lh[b], 1);
        } else bkt[i] = -1;
    }
    __syncthreads();
    for (int i = t; i < NBUCK; i += 256) {
        int c = lh[i];
        lb[i] = c ? atomicAdd(&bcur[i], c) : 0;
    }
    __syncthreads();
    #pragma unroll
    for (int i = 0; i < 16; ++i)
        if (bkt[i] >= 0) bedge[lb[bkt[i]] + rnk[i]] = val[i];
}

__global__ void k_bcnt(const unsigned int* __restrict__ bedge,
                       const int* __restrict__ bbase, int* __restrict__ cnt) {
    __shared__ int lh[BWN];
    int b = blockIdx.x, t = threadIdx.x;
    lh[t] = 0;
    __syncthreads();
    int beg = bbase[b], end = bbase[b + 1];
    for (int e = beg + t; e < end; e += 256) atomicAdd(&lh[bedge[e] >> 24], 1);
    __syncthreads();
    int n = b * BWN + t;
    if (n < NN) cnt[n] = lh[t];
}

__global__ void k_scan1(const int* __restrict__ cnt, int* __restrict__ rp,
                        int* __restrict__ bsum) {
    __shared__ int sd[256];
    int t = threadIdx.x;
    int base = blockIdx.x * 2048 + t * 8;
    int v[8];
    int s = 0;
    #pragma unroll
    for (int j = 0; j < 8; ++j) {
        int i = base + j;
        v[j] = (i < NN) ? cnt[i] : 0;
        s += v[j];
    }
    sd[t] = s;
    __syncthreads();
    for (int off = 1; off < 256; off <<= 1) {
        int xv = (t >= off) ? sd[t - off] : 0;
        __syncthreads();
        sd[t] += xv;
        __syncthreads();
    }
    int excl = sd[t] - s;
    if (t == 255) bsum[blockIdx.x] = sd[255];
    #pragma unroll
    for (int j = 0; j < 8; ++j) {
        int i = base + j;
        if (i < NN) rp[i] = excl;
        excl += v[j];
    }
}

__global__ void k_scan2(int* __restrict__ bsum) {
    if (threadIdx.x == 0 && blockIdx.x == 0) {
        int s = 0;
        for (int i = 0; i < NB_SCAN; ++i) { int c = bsum[i]; bsum[i] = s; s += c; }
    }
}

__global__ void k_scan3(int* __restrict__ rp, const int* __restrict__ bsum) {
    int i = blockIdx.x * 256 + threadIdx.x;
    if (i < NN) rp[i] += bsum[i >> 11];
    if (i == 0) rp[NN] = ET;
}

__global__ void k_place(const unsigned int* __restrict__ bedge,
                        const int* __restrict__ bbase, const int* __restrict__ rp,
                        int* __restrict__ col) {
    __shared__ int base[BWN + 1];
    __shared__ int lcur[BWN];
    __shared__ int stg[MAXS];
    int b = blockIdx.x, t = threadIdx.x;
    int n0 = b * BWN;
    for (int i = t; i <= BWN; i += 256) {
        int n = n0 + i;
        base[i] = rp[n < NN ? n : NN];
    }
    lcur[t] = 0;
    __syncthreads();
    int beg = bbase[b], end = bbase[b + 1];
    int r0 = base[0];
    int S = base[BWN] - r0;
    int lane = t & 63, w = t >> 6;
    if (S <= MAXS) {
        for (int e = beg + t; e < end; e += 256) {
            unsigned v = bedge[e];
            int i = v >> 24;
            int pos = (base[i] - r0) + atomicAdd(&lcur[i], 1);
            stg[pos] = (int)(v & 0xFFFFFFu);
        }
        __syncthreads();
        for (int i = w; i < BWN; i += 4) {
            int sb = base[i] - r0, d = base[i + 1] - base[i];
            if (d <= 1) continue;
            if (d <= 64) {
                int v = (lane < d) ? stg[sb + lane] : 0x7fffffff;
                #pragma unroll
                for (int k = 2; k <= 64; k <<= 1) {
                    #pragma unroll
                    for (int j = k >> 1; j > 0; j >>= 1) {
                        int other = __shfl_xor(v, j);
                        bool lower = (lane & j) == 0;
                        bool up = (lane & k) == 0;
                        v = (lower == up) ? min(v, other) : max(v, other);
                    }
                }
                if (lane < d) stg[sb + lane] = v;
            } else if (lane == 0) {
                for (int p = sb + 1; p < sb + d; ++p) {
                    int key = stg[p]; int j = p - 1;
                    while (j >= sb && stg[j] > key) { stg[j + 1] = stg[j]; --j; }
                    stg[j + 1] = key;
                }
            }
        }
        __syncthreads();
        for (int j = t; j < S; j += 256) col[r0 + j] = stg[j];
    } else {
        for (int e = beg + t; e < end; e += 256) {
            unsigned v = bedge[e];
            int i = v >> 24;
            int pos = base[i] + atomicAdd(&lcur[i], 1);
            col[pos] = (int)(v & 0xFFFFFFu);
        }
        __syncthreads();
        if (t < BWN) {
            int sb = base[t], d = base[t + 1] - base[t];
            for (int p = sb + 1; p < sb + d; ++p) {
                int key = col[p]; int j = p - 1;
                while (j >= sb && col[j] > key) { col[j + 1] = col[j]; --j; }
                col[j + 1] = key;
            }
        }
    }
}

// ------- Layer 1 aggregate: wave per node, 8 edges/iter, 2-deep pipeline -----------
__global__ void k_agg1(const int* __restrict__ rp, const int* __restrict__ col,
                       const __half* __restrict__ h1h, const float* __restrict__ es1,
                       const float* __restrict__ ed1, const float* __restrict__ b1,
                       float* __restrict__ out1) {
    int gid = blockIdx.x * blockDim.x + threadIdx.x;
    int n = gid >> 6, lane = threadIdx.x & 63;
    if (n >= NN) return;
    int g = lane >> 3;
    int q = lane & 7;
    float edn = ed1[n * 8 + q];
    int beg = rp[n], end = rp[n + 1];
    const uint4* h1v = (const uint4*)h1h;
    float acc[16];
    #pragma unroll
    for (int j = 0; j < 16; ++j) acc[j] = 0.f;
    float den = 0.f;
    // prologue: prefetch iteration 0 (clamped; deg >= 1 via self-loop)
    int e = beg + g;
    int ec = (e < end) ? e : end - 1;
    int s = col[ec];
    float esv = es1[s * 8 + q];
    uint4 u0 = h1v[s * 16 + q * 2];
    uint4 u1 = h1v[s * 16 + q * 2 + 1];
    while (e < end) {
        // prefetch next iteration before consuming current
        int en = e + 8;
        int ecn = (en < end) ? en : end - 1;
        int sn = col[ecn];
        float esn = es1[sn * 8 + q];
        uint4 un0 = h1v[sn * 16 + q * 2];
        uint4 un1 = h1v[sn * 16 + q * 2 + 1];
        float ex = __expf(lrelu(esv + edn));
        den += ex;
        const __half2* hp0 = (const __half2*)&u0;
        const __half2* hp1 = (const __half2*)&u1;
        #pragma unroll
        for (int j = 0; j < 4; ++j) {
            float2 f0 = __half22float2(hp0[j]);
            float2 f1 = __half22float2(hp1[j]);
            acc[j * 2]     += ex * f0.x; acc[j * 2 + 1] += ex * f0.y;
            acc[8 + j * 2] += ex * f1.x; acc[9 + j * 2] += ex * f1.y;
        }
        e = en; esv = esn; u0 = un0; u1 = un1;
    }
    #pragma unroll
    for (int o = 8; o <= 32; o <<= 1) {
        #pragma unroll
        for (int j = 0; j < 16; ++j) acc[j] += __shfl_xor(acc[j], o);
        den += __shfl_xor(den, o);
    }
    if (g == 0) {
        float inv = 1.f / (den + 1e-16f);
        #pragma unroll
        for (int i = 0; i < 4; ++i) {
            float4 b = ((const float4*)b1)[q * 4 + i];
            float4 o4;
            o4.x = fmaxf(acc[i * 4]     * inv + b.x, 0.f);
            o4.y = fmaxf(acc[i * 4 + 1] * inv + b.y, 0.f);
            o4.z = fmaxf(acc[i * 4 + 2] * inv + b.z, 0.f);
            o4.w = fmaxf(acc[i * 4 + 3] * inv + b.w, 0.f);
            ((float4*)out1)[n * 32 + q * 4 + i] = o4;
        }
    }
}

// ------- Layer 2 GEMM + logits, fused: thread-per-row, 40 acc in VGPRs -------------
__global__ __launch_bounds__(256) void k_gemm2(
        const float* __restrict__ out1, const float* __restrict__ W2,
        const float* __restrict__ as2, const float* __restrict__ ad2,
        __half* __restrict__ h2h, float* __restrict__ es2, float* __restrict__ ed2) {
    __shared__ float xs[32][257];
    int tid = threadIdx.x;
    int rbase = blockIdx.x * 256;
    int row = rbase + tid;
    float acc[40];
    #pragma unroll
    for (int c = 0; c < 40; ++c) acc[c] = 0.f;
    for (int ch = 0; ch < 4; ++ch) {
        __syncthreads();
        #pragma unroll
        for (int i = 0; i < 8; ++i) {
            int idx = tid + i * 256;
            int r = idx >> 3, j4 = idx & 7;
            int rr = rbase + r;
            float4 v = (rr < NN) ? ((const float4*)out1)[rr * 32 + ch * 8 + j4]
                                 : make_float4(0.f, 0.f, 0.f, 0.f);
            xs[j4 * 4 + 0][r] = v.x;
            xs[j4 * 4 + 1][r] = v.y;
            xs[j4 * 4 + 2][r] = v.z;
            xs[j4 * 4 + 3][r] = v.w;
        }
        __syncthreads();
        #pragma unroll 4
        for (int j = 0; j < 32; ++j) {
            float xk = xs[j][tid];
            const float* wrow = W2 + (ch * 32 + j) * 40;
            #pragma unroll
            for (int c = 0; c < 40; ++c) acc[c] += xk * wrow[c];
        }
    }
    if (row < NN) {
        float s = 0.f, d = 0.f;
        #pragma unroll
        for (int c = 0; c < 40; ++c) { s += acc[c] * as2[c]; d += acc[c] * ad2[c]; }
        es2[row] = s;
        ed2[row] = d;
        union { __half2 h[20]; uint4 u[5]; } cv;
        #pragma unroll
        for (int c = 0; c < 20; ++c)
            cv.h[c] = __floats2half2_rn(acc[c * 2], acc[c * 2 + 1]);
        #pragma unroll
        for (int i = 0; i < 5; ++i) ((uint4*)h2h)[row * 5 + i] = cv.u[i];
    }
}

// -- Layer 2 aggregate + log_softmax: wave per node, 8 edges/iter, 2-deep pipeline --
__global__ void k_agg2(const int* __restrict__ rp, const int* __restrict__ col,
                       const __half* __restrict__ h2h, const float* __restrict__ es2,
                       const float* __restrict__ ed2, const float* __restrict__ b2,
                       float* __restrict__ out) {
    int gid = blockIdx.x * blockDim.x + threadIdx.x;
    int n = gid >> 6, lane = threadIdx.x & 63;
    if (n >= NN) return;
    int g = lane >> 3;
    int q = lane & 7;
    bool qv = q < 5;
    float edn = ed2[n];
    int beg = rp[n], end = rp[n + 1];
    const uint4* h2v = (const uint4*)h2h;
    float acc[8];
    #pragma unroll
    for (int j = 0; j < 8; ++j) acc[j] = 0.f;
    float den = 0.f;
    int e = beg + g;
    int ec = (e < end) ? e : end - 1;
    int s = col[ec];
    float esv = es2[s];
    uint4 u = qv ? h2v[s * 5 + q] : make_uint4(0, 0, 0, 0);
    while (e < end) {
        int en = e + 8;
        int ecn = (en < end) ? en : end - 1;
        int sn = col[ecn];
        float esn = es2[sn];
        uint4 un = qv ? h2v[sn * 5 + q] : make_uint4(0, 0, 0, 0);
        float ex = __expf(lrelu(esv + edn));
        den += ex;
        const __half2* hp = (const __half2*)&u;
        #pragma unroll
        for (int j = 0; j < 4; ++j) {
            float2 f = __half22float2(hp[j]);
            acc[j * 2]     += ex * f.x;
            acc[j * 2 + 1] += ex * f.y;
        }
        e = en; esv = esn; u = un;
    }
    #pragma unroll
    for (int o = 8; o <= 32; o <<= 1) {
        #pragma unroll
        for (int j = 0; j < 8; ++j) acc[j] += __shfl_xor(acc[j], o);
        den += __shfl_xor(den, o);
    }
    float inv = 1.f / (den + 1e-16f);
    float v[8];
    float m = -INFINITY;
    if (qv) {
        #pragma unroll
        for (int j = 0; j < 8; ++j) {
            v[j] = acc[j] * inv + b2[q * 8 + j];
            m = fmaxf(m, v[j]);
        }
    }
    #pragma unroll
    for (int o = 1; o <= 4; o <<= 1) m = fmaxf(m, __shfl_xor(m, o));
    float es = 0.f;
    if (qv) {
        #pragma unroll
        for (int j = 0; j < 8; ++j) es += __expf(v[j] - m);
    }
    #pragma unroll
    for (int o = 1; o <= 4; o <<= 1) es += __shfl_xor(es, o);
    if (g == 0 && qv) {
        float ls = m + __logf(es);
        float4 o0, o1;
        o0.x = v[0] - ls; o0.y = v[1] - ls; o0.z = v[2] - ls; o0.w = v[3] - ls;
        o1.x = v[4] - ls; o1.y = v[5] - ls; o1.z = v[6] - ls; o1.w = v[7] - ls;
        ((float4*)out)[n * 10 + q * 2]     = o0;
        ((float4*)out)[n * 10 + q * 2 + 1] = o1;
    }
}

extern "C" void kernel_launch(void* const* d_in, const int* in_sizes, int n_in,
                              void* d_out, int out_size, void* d_ws, size_t ws_size,
                              hipStream_t stream) {
    const float* x   = (const float*)d_in[0];
    const int*   ei  = (const int*)d_in[1];   // int32 (JAX x64 disabled)
    const float* W1  = (const float*)d_in[2];
    const float* as1 = (const float*)d_in[3];
    const float* ad1 = (const float*)d_in[4];
    const float* b1  = (const float*)d_in[5];
    const float* W2  = (const float*)d_in[6];
    const float* as2 = (const float*)d_in[7];
    const float* ad2 = (const float*)d_in[8];
    const float* b2  = (const float*)d_in[9];
    float* out = (float*)d_out;

    const int* esrc = ei;
    const int* edst = ei + EE;

    // workspace layout
    __half* h1h = (__half*)d_ws;               // N*128 fp16
    float* es1  = (float*)(h1h + NN * 128);    // N*8
    float* ed1  = es1 + NN * 8;                // N*8
    float* out1 = ed1 + NN * 8;                // N*128 fp32
    __half* h2h = (__half*)(out1 + NN * 128);  // N*40 fp16
    float* es2  = (float*)(h2h + NN * 40);     // N
    float* ed2  = es2 + NN;                    // N
    int* rp     = (int*)(ed2 + NN);            // N+1
    int* bsum   = rp + NN + 1;                 // 64
    int* cnt    = bsum + 64;                   // N
    int* col    = cnt + NN;                    // ET
    int* bcnt   = col + ET;                    // NBUCK
    int* bbase  = bcnt + NBUCK;                // NBUCK+1
    int* bcur   = bbase + NBUCK + 1;           // NBUCK
    unsigned int* bedge = (unsigned int*)(bcur + NBUCK);  // ET
    __half* w1p = (__half*)(bedge + ET);       // 32768 fp16 (64 KB)

    // CSR build: bucket sort -> per-node counts -> scan -> place(+sort in LDS)
    hipMemsetAsync(bcnt, 0, NBUCK * sizeof(int), stream);
    k_bhist<<<NAB, 256, 0, stream>>>(edst, bcnt);
    k_bscan<<<1, 256, 0, stream>>>(bcnt, bbase, bcur);
    k_bscatter<<<NAB, 256, 0, stream>>>(esrc, edst, bcur, bedge);
    k_bcnt<<<NBUCK, 256, 0, stream>>>(bedge, bbase, cnt);
    k_scan1<<<NB_SCAN, 256, 0, stream>>>(cnt, rp, bsum);
    k_scan2<<<1, 64, 0, stream>>>(bsum);
    k_scan3<<<(NN + 255) / 256, 256, 0, stream>>>(rp, bsum);
    k_place<<<NBUCK, 256, 0, stream>>>(bedge, bbase, rp, col);

    // layer 1 (MFMA gemm, swapped operands)
    k_w1pack<<<128, 256, 0, stream>>>(W1, w1p);
    k_gemm1<<<(NN + 63) / 64, 256, 0, stream>>>(x, w1p, as1, ad1, h1h, es1, ed1);
    k_agg1<<<(NN * 64) / 256, 256, 0, stream>>>(rp, col, h1h, es1, ed1, b1, out1);

    // layer 2 (gemm2 fused with logits2)
    k_gemm2<<<(NN + 255) / 256, 256, 0, stream>>>(out1, W2, as2, ad2, h2h, es2, ed2);
    k_agg2<<<(NN * 64) / 256, 256, 0, stream>>>(rp, col, h2h, es2, ed2, b2, out);
}

// Round 9
// 344.907 us; speedup vs baseline: 2.4658x; 1.0599x over previous
//
#include <hip/hip_runtime.h>
#include <hip/hip_fp16.h>
#include <math.h>

#define NN 100000
#define EE 1600000
#define ET (EE + NN)
#define BWN 256       // nodes per bucket
#define NBUCK 391     // ceil(NN/BWN)
#define ACHUNK 4096   // edges per bucket-scatter block
#define NAB 416       // ceil(ET/ACHUNK)
#define MAXS 6144     // LDS staging cap (mean 4352, sd 64 -> +28 sigma)

typedef _Float16 f16x8 __attribute__((ext_vector_type(8)));
typedef float f32x4 __attribute__((ext_vector_type(4)));

__device__ __forceinline__ float lrelu(float x) { return x > 0.f ? x : 0.2f * x; }

// ---- W1 fragment pack: plane 0 = fp16(W1), plane 1 = fp16 residual ----------------
__global__ void k_w1pack(const float* __restrict__ W1, __half* __restrict__ w1p) {
    int idx = blockIdx.x * 256 + threadIdx.x;   // 0..32767
    int j = idx & 7, lane = (idx >> 3) & 63, k0 = (idx >> 9) & 3;
    int ct = (idx >> 11) & 7, plane = idx >> 14;
    int k = k0 * 32 + (lane >> 4) * 8 + j;
    int c = ct * 16 + (lane & 15);
    float w = W1[k * 128 + c];
    _Float16 wh = (_Float16)w;
    _Float16 v = plane ? (_Float16)(w - (float)wh) : wh;
    w1p[idx] = *(__half*)&v;
}

// ---- Layer 1 GEMM via MFMA (error-compensated fp16), swapped operands -------------
__global__ __launch_bounds__(256) void k_gemm1(
        const float* __restrict__ x, const __half* __restrict__ w1p,
        const float* __restrict__ as1, const float* __restrict__ ad1,
        __half* __restrict__ h1h, float* __restrict__ es1, float* __restrict__ ed1) {
    int tid = threadIdx.x;
    int w = tid >> 6, lane = tid & 63;
    int rb = blockIdx.x * 64 + w * 16;
    int l15 = lane & 15, rg = lane >> 4;

    int arow = rb + l15;
    bool aok = arow < NN;
    const float4* x4 = (const float4*)x;
    f16x8 ah[4], ar[4];
    #pragma unroll
    for (int k0 = 0; k0 < 4; ++k0) {
        float4 p0 = make_float4(0.f, 0.f, 0.f, 0.f), p1 = p0;
        if (aok) {
            int fi = arow * 32 + k0 * 8 + rg * 2;
            p0 = x4[fi];
            p1 = x4[fi + 1];
        }
        float pv[8] = {p0.x, p0.y, p0.z, p0.w, p1.x, p1.y, p1.z, p1.w};
        #pragma unroll
        for (int j = 0; j < 8; ++j) {
            _Float16 h = (_Float16)pv[j];
            ah[k0][j] = h;
            ar[k0][j] = (_Float16)(pv[j] - (float)h);
        }
    }

    const f16x8* w1f = (const f16x8*)w1p;   // [plane:2][ct:8][k0:4][lane:64]
    f32x4 acc[8];
    #pragma unroll
    for (int ct = 0; ct < 8; ++ct) acc[ct] = (f32x4){0.f, 0.f, 0.f, 0.f};
    #pragma unroll
    for (int ct = 0; ct < 8; ++ct) {
        #pragma unroll
        for (int k0 = 0; k0 < 4; ++k0) {
            f16x8 bh = w1f[(ct * 4 + k0) * 64 + lane];
            f16x8 br = w1f[2048 + (ct * 4 + k0) * 64 + lane];
            acc[ct] = __builtin_amdgcn_mfma_f32_16x16x32_f16(bh, ah[k0], acc[ct], 0, 0, 0);
            acc[ct] = __builtin_amdgcn_mfma_f32_16x16x32_f16(bh, ar[k0], acc[ct], 0, 0, 0);
            acc[ct] = __builtin_amdgcn_mfma_f32_16x16x32_f16(br, ah[k0], acc[ct], 0, 0, 0);
        }
    }

    int row = rb + l15;
    bool rok = row < NN;
    #pragma unroll
    for (int ct = 0; ct < 8; ++ct) {
        if (rok) {
            union { __half2 h[2]; uint2 u; } cv;
            cv.h[0] = __floats2half2_rn(acc[ct][0], acc[ct][1]);
            cv.h[1] = __floats2half2_rn(acc[ct][2], acc[ct][3]);
            *(uint2*)&h1h[row * 128 + ct * 16 + rg * 4] = cv.u;
        }
        float4 a4 = ((const float4*)as1)[ct * 4 + rg];
        float4 d4 = ((const float4*)ad1)[ct * 4 + rg];
        float s = acc[ct][0] * a4.x + acc[ct][1] * a4.y + acc[ct][2] * a4.z + acc[ct][3] * a4.w;
        float d = acc[ct][0] * d4.x + acc[ct][1] * d4.y + acc[ct][2] * d4.z + acc[ct][3] * d4.w;
        s += __shfl_xor(s, 16); s += __shfl_xor(s, 32);
        d += __shfl_xor(d, 16); d += __shfl_xor(d, 32);
        if (rg == 0 && rok) { es1[row * 8 + ct] = s; ed1[row * 8 + ct] = d; }
    }
}

// ================= CSR build: two-level bucket sort (write-amp-free) ===============
__global__ void k_bhist(const int* __restrict__ dst, int* __restrict__ bcnt) {
    __shared__ int lh[NBUCK];
    int t = threadIdx.x;
    for (int i = t; i < NBUCK; i += 256) lh[i] = 0;
    __syncthreads();
    int c0 = blockIdx.x * ACHUNK;
    #pragma unroll
    for (int i = 0; i < 16; ++i) {
        int e = c0 + t + i * 256;
        if (e < ET) {
            int d = (e < EE) ? dst[e] : e - EE;
            atomicAdd(&lh[d >> 8], 1);
        }
    }
    __syncthreads();
    for (int i = t; i < NBUCK; i += 256) {
        int c = lh[i];
        if (c) atomicAdd(&bcnt[i], c);
    }
}

__global__ void k_bscan(const int* __restrict__ bcnt, int* __restrict__ bbase,
                        int* __restrict__ bcur) {
    __shared__ int sd[256];
    int t = threadIdx.x;
    int i0 = 2 * t, i1 = 2 * t + 1;
    int v0 = (i0 < NBUCK) ? bcnt[i0] : 0;
    int v1 = (i1 < NBUCK) ? bcnt[i1] : 0;
    int s = v0 + v1;
    sd[t] = s;
    __syncthreads();
    for (int off = 1; off < 256; off <<= 1) {
        int xv = (t >= off) ? sd[t - off] : 0;
        __syncthreads();
        sd[t] += xv;
        __syncthreads();
    }
    int excl = sd[t] - s;
    if (i0 <= NBUCK) { bbase[i0] = excl; if (i0 < NBUCK) bcur[i0] = excl; }
    if (i1 <= NBUCK) { bbase[i1] = excl + v0; if (i1 < NBUCK) bcur[i1] = excl + v0; }
}

__global__ void k_bscatter(const int* __restrict__ src, const int* __restrict__ dst,
                           int* __restrict__ bcur, unsigned int* __restrict__ bedge) {
    __shared__ int lh[NBUCK];
    __shared__ int lb[NBUCK];
    int t = threadIdx.x;
    for (int i = t; i < NBUCK; i += 256) lh[i] = 0;
    __syncthreads();
    int c0 = blockIdx.x * ACHUNK;
    unsigned int val[16];
    int bkt[16];
    int rnk[16];
    #pragma unroll
    for (int i = 0; i < 16; ++i) {
        int e = c0 + t + i * 256;
        if (e < ET) {
            int s, d;
            if (e < EE) { s = src[e]; d = dst[e]; } else { s = d = e - EE; }
            int b = d >> 8;
            bkt[i] = b;
            val[i] = (unsigned)s | ((unsigned)(d & 255) << 24);
            rnk[i] = atomicAdd(&lh[b], 1);
        } else bkt[i] = -1;
    }
    __syncthreads();
    for (int i = t; i < NBUCK; i += 256) {
        int c = lh[i];
        lb[i] = c ? atomicAdd(&bcur[i], c) : 0;
    }
    __syncthreads();
    #pragma unroll
    for (int i = 0; i < 16; ++i)
        if (bkt[i] >= 0) bedge[lb[bkt[i]] + rnk[i]] = val[i];
}

// per-node counts + intra-bucket scan -> rp directly (replaces bcnt + 3 scan kernels)
__global__ void k_brp(const unsigned int* __restrict__ bedge,
                      const int* __restrict__ bbase, int* __restrict__ rp) {
    __shared__ int lh[BWN];
    __shared__ int sc[BWN];
    int b = blockIdx.x, t = threadIdx.x;
    lh[t] = 0;
    __syncthreads();
    int beg = bbase[b], end = bbase[b + 1];
    for (int e = beg + t; e < end; e += 256) atomicAdd(&lh[bedge[e] >> 24], 1);
    __syncthreads();
    int v = lh[t];
    sc[t] = v;
    __syncthreads();
    for (int off = 1; off < 256; off <<= 1) {
        int xv = (t >= off) ? sc[t - off] : 0;
        __syncthreads();
        sc[t] += xv;
        __syncthreads();
    }
    int n = b * BWN + t;
    if (n < NN) rp[n] = beg + sc[t] - v;   // exclusive prefix + bucket base
    if (b == 0 && t == 0) rp[NN] = ET;
}

__global__ void k_place(const unsigned int* __restrict__ bedge,
                        const int* __restrict__ bbase, const int* __restrict__ rp,
                        int* __restrict__ col) {
    __shared__ int base[BWN + 1];
    __shared__ int lcur[BWN];
    __shared__ int stg[MAXS];
    int b = blockIdx.x, t = threadIdx.x;
    int n0 = b * BWN;
    for (int i = t; i <= BWN; i += 256) {
        int n = n0 + i;
        base[i] = rp[n < NN ? n : NN];
    }
    lcur[t] = 0;
    __syncthreads();
    int beg = bbase[b], end = bbase[b + 1];
    int r0 = base[0];
    int S = base[BWN] - r0;
    int lane = t & 63, w = t >> 6;
    if (S <= MAXS) {
        for (int e = beg + t; e < end; e += 256) {
            unsigned v = bedge[e];
            int i = v >> 24;
            int pos = (base[i] - r0) + atomicAdd(&lcur[i], 1);
            stg[pos] = (int)(v & 0xFFFFFFu);
        }
        __syncthreads();
        for (int i = w; i < BWN; i += 4) {
            int sb = base[i] - r0, d = base[i + 1] - base[i];
            if (d <= 1) continue;
            if (d <= 64) {
                int v = (lane < d) ? stg[sb + lane] : 0x7fffffff;
                #pragma unroll
                for (int k = 2; k <= 64; k <<= 1) {
                    #pragma unroll
                    for (int j = k >> 1; j > 0; j >>= 1) {
                        int other = __shfl_xor(v, j);
                        bool lower = (lane & j) == 0;
                        bool up = (lane & k) == 0;
                        v = (lower == up) ? min(v, other) : max(v, other);
                    }
                }
                if (lane < d) stg[sb + lane] = v;
            } else if (lane == 0) {
                for (int p = sb + 1; p < sb + d; ++p) {
                    int key = stg[p]; int j = p - 1;
                    while (j >= sb && stg[j] > key) { stg[j + 1] = stg[j]; --j; }
                    stg[j + 1] = key;
                }
            }
        }
        __syncthreads();
        for (int j = t; j < S; j += 256) col[r0 + j] = stg[j];
    } else {
        for (int e = beg + t; e < end; e += 256) {
            unsigned v = bedge[e];
            int i = v >> 24;
            int pos = base[i] + atomicAdd(&lcur[i], 1);
            col[pos] = (int)(v & 0xFFFFFFu);
        }
        __syncthreads();
        if (t < BWN) {
            int sb = base[t], d = base[t + 1] - base[t];
            for (int p = sb + 1; p < sb + d; ++p) {
                int key = col[p]; int j = p - 1;
                while (j >= sb && col[j] > key) { col[j + 1] = col[j]; --j; }
                col[j + 1] = key;
            }
        }
    }
}

// --- Layer 1 aggregate: 8 lanes per node, lane = head, edges serial, no shuffles ---
__global__ void k_agg1(const int* __restrict__ rp, const int* __restrict__ col,
                       const __half* __restrict__ h1h, const float* __restrict__ es1,
                       const float* __restrict__ ed1, const float* __restrict__ b1,
                       float* __restrict__ out1) {
    int gid = blockIdx.x * blockDim.x + threadIdx.x;
    int n = gid >> 3;             // node = 8-lane group
    int l = threadIdx.x & 7;      // lane-in-group = head, channels l*16..l*16+15
    if (n >= NN) return;
    float edn = ed1[n * 8 + l];
    int beg = rp[n], end = rp[n + 1];
    const uint4* h1v = (const uint4*)h1h;
    float acc[16];
    #pragma unroll
    for (int j = 0; j < 16; ++j) acc[j] = 0.f;
    float den = 0.f;
    // 2-deep prefetch, edges serial (deg >= 1 via self-loop)
    int e = beg;
    int s = col[e];
    float esv = es1[s * 8 + l];
    uint4 u0 = h1v[s * 16 + l * 2];
    uint4 u1 = h1v[s * 16 + l * 2 + 1];
    while (e < end) {
        int en = e + 1;
        int ecn = (en < end) ? en : e;
        int sn = col[ecn];
        float esn = es1[sn * 8 + l];
        uint4 un0 = h1v[sn * 16 + l * 2];
        uint4 un1 = h1v[sn * 16 + l * 2 + 1];
        float ex = __expf(lrelu(esv + edn));
        den += ex;
        const __half2* hp0 = (const __half2*)&u0;
        const __half2* hp1 = (const __half2*)&u1;
        #pragma unroll
        for (int j = 0; j < 4; ++j) {
            float2 f0 = __half22float2(hp0[j]);
            float2 f1 = __half22float2(hp1[j]);
            acc[j * 2]     += ex * f0.x; acc[j * 2 + 1] += ex * f0.y;
            acc[8 + j * 2] += ex * f1.x; acc[9 + j * 2] += ex * f1.y;
        }
        e = en; esv = esn; u0 = un0; u1 = un1;
    }
    float inv = 1.f / (den + 1e-16f);
    #pragma unroll
    for (int i = 0; i < 4; ++i) {
        float4 b = ((const float4*)b1)[l * 4 + i];
        float4 o4;
        o4.x = fmaxf(acc[i * 4]     * inv + b.x, 0.f);
        o4.y = fmaxf(acc[i * 4 + 1] * inv + b.y, 0.f);
        o4.z = fmaxf(acc[i * 4 + 2] * inv + b.z, 0.f);
        o4.w = fmaxf(acc[i * 4 + 3] * inv + b.w, 0.f);
        ((float4*)out1)[n * 32 + l * 4 + i] = o4;
    }
}

// ------- Layer 2 GEMM + logits, fused: thread-per-row, 40 acc in VGPRs -------------
__global__ __launch_bounds__(256) void k_gemm2(
        const float* __restrict__ out1, const float* __restrict__ W2,
        const float* __restrict__ as2, const float* __restrict__ ad2,
        __half* __restrict__ h2h, float* __restrict__ es2, float* __restrict__ ed2) {
    __shared__ float xs[32][257];
    int tid = threadIdx.x;
    int rbase = blockIdx.x * 256;
    int row = rbase + tid;
    float acc[40];
    #pragma unroll
    for (int c = 0; c < 40; ++c) acc[c] = 0.f;
    for (int ch = 0; ch < 4; ++ch) {
        __syncthreads();
        #pragma unroll
        for (int i = 0; i < 8; ++i) {
            int idx = tid + i * 256;
            int r = idx >> 3, j4 = idx & 7;
            int rr = rbase + r;
            float4 v = (rr < NN) ? ((const float4*)out1)[rr * 32 + ch * 8 + j4]
                                 : make_float4(0.f, 0.f, 0.f, 0.f);
            xs[j4 * 4 + 0][r] = v.x;
            xs[j4 * 4 + 1][r] = v.y;
            xs[j4 * 4 + 2][r] = v.z;
            xs[j4 * 4 + 3][r] = v.w;
        }
        __syncthreads();
        #pragma unroll 4
        for (int j = 0; j < 32; ++j) {
            float xk = xs[j][tid];
            const float* wrow = W2 + (ch * 32 + j) * 40;
            #pragma unroll
            for (int c = 0; c < 40; ++c) acc[c] += xk * wrow[c];
        }
    }
    if (row < NN) {
        float s = 0.f, d = 0.f;
        #pragma unroll
        for (int c = 0; c < 40; ++c) { s += acc[c] * as2[c]; d += acc[c] * ad2[c]; }
        es2[row] = s;
        ed2[row] = d;
        union { __half2 h[20]; uint4 u[5]; } cv;
        #pragma unroll
        for (int c = 0; c < 20; ++c)
            cv.h[c] = __floats2half2_rn(acc[c * 2], acc[c * 2 + 1]);
        #pragma unroll
        for (int i = 0; i < 5; ++i) ((uint4*)h2h)[row * 5 + i] = cv.u[i];
    }
}

// -- Layer 2 aggregate + log_softmax: 8 lanes per node (5 active), edges serial -----
__global__ void k_agg2(const int* __restrict__ rp, const int* __restrict__ col,
                       const __half* __restrict__ h2h, const float* __restrict__ es2,
                       const float* __restrict__ ed2, const float* __restrict__ b2,
                       float* __restrict__ out) {
    int gid = blockIdx.x * blockDim.x + threadIdx.x;
    int n = gid >> 3;             // node = 8-lane group
    int l = threadIdx.x & 7;      // channel block l*8..l*8+7, active l<5
    if (n >= NN) return;
    bool qv = l < 5;
    float edn = ed2[n];
    int beg = rp[n], end = rp[n + 1];
    const uint4* h2v = (const uint4*)h2h;
    float acc[8];
    #pragma unroll
    for (int j = 0; j < 8; ++j) acc[j] = 0.f;
    float den = 0.f;
    int e = beg;
    int s = col[e];
    float esv = es2[s];
    uint4 u = qv ? h2v[s * 5 + l] : make_uint4(0, 0, 0, 0);
    while (e < end) {
        int en = e + 1;
        int ecn = (en < end) ? en : e;
        int sn = col[ecn];
        float esn = es2[sn];
        uint4 un = qv ? h2v[sn * 5 + l] : make_uint4(0, 0, 0, 0);
        float ex = __expf(lrelu(esv + edn));
        den += ex;
        const __half2* hp = (const __half2*)&u;
        #pragma unroll
        for (int j = 0; j < 4; ++j) {
            float2 f = __half22float2(hp[j]);
            acc[j * 2]     += ex * f.x;
            acc[j * 2 + 1] += ex * f.y;
        }
        e = en; esv = esn; u = un;
    }
    float inv = 1.f / (den + 1e-16f);
    float v[8];
    float m = -INFINITY;
    if (qv) {
        #pragma unroll
        for (int j = 0; j < 8; ++j) {
            v[j] = acc[j] * inv + b2[l * 8 + j];
            m = fmaxf(m, v[j]);
        }
    }
    // reduce across the 8-lane group (xor 1,2,4 stays within the group)
    #pragma unroll
    for (int o = 1; o <= 4; o <<= 1) m = fmaxf(m, __shfl_xor(m, o));
    float es = 0.f;
    if (qv) {
        #pragma unroll
        for (int j = 0; j < 8; ++j) es += __expf(v[j] - m);
    }
    #pragma unroll
    for (int o = 1; o <= 4; o <<= 1) es += __shfl_xor(es, o);
    if (qv) {
        float ls = m + __logf(es);
        float4 o0, o1;
        o0.x = v[0] - ls; o0.y = v[1] - ls; o0.z = v[2] - ls; o0.w = v[3] - ls;
        o1.x = v[4] - ls; o1.y = v[5] - ls; o1.z = v[6] - ls; o1.w = v[7] - ls;
        ((float4*)out)[n * 10 + l * 2]     = o0;
        ((float4*)out)[n * 10 + l * 2 + 1] = o1;
    }
}

extern "C" void kernel_launch(void* const* d_in, const int* in_sizes, int n_in,
                              void* d_out, int out_size, void* d_ws, size_t ws_size,
                              hipStream_t stream) {
    const float* x   = (const float*)d_in[0];
    const int*   ei  = (const int*)d_in[1];   // int32 (JAX x64 disabled)
    const float* W1  = (const float*)d_in[2];
    const float* as1 = (const float*)d_in[3];
    const float* ad1 = (const float*)d_in[4];
    const float* b1  = (const float*)d_in[5];
    const float* W2  = (const float*)d_in[6];
    const float* as2 = (const float*)d_in[7];
    const float* ad2 = (const float*)d_in[8];
    const float* b2  = (const float*)d_in[9];
    float* out = (float*)d_out;

    const int* esrc = ei;
    const int* edst = ei + EE;

    // workspace layout
    __half* h1h = (__half*)d_ws;               // N*128 fp16
    float* es1  = (float*)(h1h + NN * 128);    // N*8
    float* ed1  = es1 + NN * 8;                // N*8
    float* out1 = ed1 + NN * 8;                // N*128 fp32
    __half* h2h = (__half*)(out1 + NN * 128);  // N*40 fp16
    float* es2  = (float*)(h2h + NN * 40);     // N
    float* ed2  = es2 + NN;                    // N
    int* rp     = (int*)(ed2 + NN);            // N+1
    int* col    = rp + NN + 1;                 // ET
    int* bcnt   = col + ET;                    // NBUCK
    int* bbase  = bcnt + NBUCK;                // NBUCK+1
    int* bcur   = bbase + NBUCK + 1;           // NBUCK
    unsigned int* bedge = (unsigned int*)(bcur + NBUCK);  // ET
    __half* w1p = (__half*)(bedge + ET);       // 32768 fp16 (64 KB)

    // CSR build: bucket sort -> rp (fused scan) -> place(+sort in LDS)
    hipMemsetAsync(bcnt, 0, NBUCK * sizeof(int), stream);
    k_bhist<<<NAB, 256, 0, stream>>>(edst, bcnt);
    k_bscan<<<1, 256, 0, stream>>>(bcnt, bbase, bcur);
    k_bscatter<<<NAB, 256, 0, stream>>>(esrc, edst, bcur, bedge);
    k_brp<<<NBUCK, 256, 0, stream>>>(bedge, bbase, rp);
    k_place<<<NBUCK, 256, 0, stream>>>(bedge, bbase, rp, col);

    // layer 1 (MFMA gemm, swapped operands)
    k_w1pack<<<128, 256, 0, stream>>>(W1, w1p);
    k_gemm1<<<(NN + 63) / 64, 256, 0, stream>>>(x, w1p, as1, ad1, h1h, es1, ed1);
    k_agg1<<<(NN * 8 + 255) / 256, 256, 0, stream>>>(rp, col, h1h, es1, ed1, b1, out1);

    // layer 2 (gemm2 fused with logits2)
    k_gemm2<<<(NN + 255) / 256, 256, 0, stream>>>(out1, W2, as2, ad2, h2h, es2, ed2);
    k_agg2<<<(NN * 8 + 255) / 256, 256, 0, stream>>>(rp, col, h2h, es2, ed2, b2, out);
}